// Round 18
// baseline (71.098 us; speedup 1.0000x reference)
//
#include <hip/hip_runtime.h>
#include <math.h>

#define EPSBN 1e-3f

// geometry
#define BB 4
#define TT 4
#define C2 512
#define H2 20
#define W2 20
#define HW2 400
#define RR 4
#define KK 9
#define NS 81
#define NT 3
#define NTS 243
#define HID 4

typedef __attribute__((ext_vector_type(8))) short short8;
typedef __attribute__((ext_vector_type(4))) float floatx4;

static __device__ inline unsigned short f2bf(float f) {
    unsigned int u = __float_as_uint(f);
    unsigned int r = (u + 0x7fffu + ((u >> 16) & 1u)) >> 16;
    return (unsigned short)r;
}

// ---------------------------------------------------------------------------
// prep_frag: conv2 weights -> bf16 MFMA-fragment layout (R12/R13-validated)
// ---------------------------------------------------------------------------
static __device__ inline void prep_frag_body(
    int i,
    const float* __restrict__ w0, const float* __restrict__ w1,
    const float* __restrict__ w2,
    const float* __restrict__ g0, const float* __restrict__ b0,
    const float* __restrict__ m0, const float* __restrict__ v0,
    const float* __restrict__ g1, const float* __restrict__ b1,
    const float* __restrict__ m1, const float* __restrict__ v1,
    const float* __restrict__ g2, const float* __restrict__ b2,
    const float* __restrict__ m2, const float* __restrict__ v2,
    unsigned short* __restrict__ wb0, unsigned short* __restrict__ wb1,
    unsigned short* __restrict__ wb2, float* __restrict__ shift) {
    if (i < 20480) {  // L0: KB=5
        int j = i & 7, lane = (i >> 3) & 63;
        int blk = i >> 9;
        int kb = blk % 5, o16 = blk / 5;
        int o = o16 * 16 + (lane & 15);
        int k = kb * 32 + (lane >> 4) * 8 + j;
        float sc = g0[o] * rsqrtf(v0[o] + EPSBN);
        wb0[i] = f2bf(k < 132 ? w0[o * 132 + k] * sc : 0.f);
        return;
    }
    i -= 20480;
    if (i < 73728) {  // L1: KB=9
        int j = i & 7, lane = (i >> 3) & 63;
        int blk = i >> 9;
        int kb = blk % 9, o16 = blk / 9;
        int o = o16 * 16 + (lane & 15);
        int k = kb * 32 + (lane >> 4) * 8 + j;
        float sc = g1[o] * rsqrtf(v1[o] + EPSBN);
        wb1[i] = f2bf(k < 260 ? w1[o * 260 + k] * sc : 0.f);
        return;
    }
    i -= 73728;
    if (i < 278528) {  // L2: KB=17
        int j = i & 7, lane = (i >> 3) & 63;
        int blk = i >> 9;
        int kb = blk % 17, o16 = blk / 17;
        int o = o16 * 16 + (lane & 15);
        int k = kb * 32 + (lane >> 4) * 8 + j;
        float sc = g2[o] * rsqrtf(v2[o] + EPSBN);
        wb2[i] = f2bf(k < 516 ? w2[o * 516 + k] * sc : 0.f);
        return;
    }
    i -= 278528;
    if (i < 896) {
        if (i < 128) {
            float sc = g0[i] * rsqrtf(v0[i] + EPSBN);
            shift[i] = b0[i] - m0[i] * sc;
        } else if (i < 384) {
            int o = i - 128;
            float sc = g1[o] * rsqrtf(v1[o] + EPSBN);
            shift[i] = b1[o] - m1[o] * sc;
        } else {
            int o = i - 384;
            float sc = g2[o] * rsqrtf(v2[o] + EPSBN);
            shift[i] = b2[o] - m2[o] * sc;
        }
    }
}

// linear prep (fallback path, R1-validated)
static __device__ inline void prep_body(
    int i,
    const float* __restrict__ w0, const float* __restrict__ w1,
    const float* __restrict__ w2,
    const float* __restrict__ g0, const float* __restrict__ b0,
    const float* __restrict__ m0, const float* __restrict__ v0,
    const float* __restrict__ g1, const float* __restrict__ b1,
    const float* __restrict__ m1, const float* __restrict__ v1,
    const float* __restrict__ g2, const float* __restrict__ b2,
    const float* __restrict__ m2, const float* __restrict__ v2,
    unsigned short* __restrict__ wb0, unsigned short* __restrict__ wb1,
    unsigned short* __restrict__ wb2, float* __restrict__ shift) {
    if (i < 128 * 160) {
        int o = i / 160, k = i % 160;
        float sc = g0[o] * rsqrtf(v0[o] + EPSBN);
        wb0[i] = f2bf(k < 132 ? w0[o * 132 + k] * sc : 0.f);
        return;
    }
    i -= 128 * 160;
    if (i < 256 * 288) {
        int o = i / 288, k = i % 288;
        float sc = g1[o] * rsqrtf(v1[o] + EPSBN);
        wb1[i] = f2bf(k < 260 ? w1[o * 260 + k] * sc : 0.f);
        return;
    }
    i -= 256 * 288;
    if (i < 512 * 544) {
        int o = i / 544, k = i % 544;
        float sc = g2[o] * rsqrtf(v2[o] + EPSBN);
        wb2[i] = f2bf(k < 516 ? w2[o * 516 + k] * sc : 0.f);
        return;
    }
    i -= 512 * 544;
    if (i < 896) {
        if (i < 128) {
            float sc = g0[i] * rsqrtf(v0[i] + EPSBN);
            shift[i] = b0[i] - m0[i] * sc;
        } else if (i < 384) {
            int o = i - 128;
            float sc = g1[o] * rsqrtf(v1[o] + EPSBN);
            shift[i] = b1[o] - m1[o] * sc;
        } else {
            int o = i - 384;
            float sc = g2[o] * rsqrtf(v2[o] + EPSBN);
            shift[i] = b2[o] - m2[o] * sc;
        }
    }
}

__global__ void k_prep(const float* w0, const float* w1, const float* w2,
                       const float* g0, const float* b0, const float* m0, const float* v0,
                       const float* g1, const float* b1, const float* m1, const float* v1,
                       const float* g2, const float* b2, const float* m2, const float* v2,
                       unsigned short* wb0, unsigned short* wb1,
                       unsigned short* wb2, float* shift) {
    int i = blockIdx.x * 256 + threadIdx.x;
    prep_body(i, w0, w1, w2, g0, b0, m0, v0, g1, b1, m1, v1, g2, b2, m2, v2,
              wb0, wb1, wb2, shift);
}

// ---------------------------------------------------------------------------
// K_prep_pad: fused fragment-prep + zero-padded last-frame copy (R13-validated)
// ---------------------------------------------------------------------------
__global__ void k_prep_pad(const float* __restrict__ f2, float* __restrict__ pad,
                           const float* w0, const float* w1, const float* w2,
                           const float* g0, const float* b0, const float* m0, const float* v0,
                           const float* g1, const float* b1, const float* m1, const float* v1,
                           const float* g2, const float* b2, const float* m2, const float* v2,
                           unsigned short* wb0, unsigned short* wb1,
                           unsigned short* wb2, float* shift) {
    int bid = blockIdx.x;
    if (bid < 1792) {
        int id = bid * 256 + threadIdx.x;           // float4 index
        if (id >= BB * C2 * 28 * 8) return;
        int c4 = id & 7;
        int tmp = id >> 3;
        int r = tmp % 28;
        int tmp2 = tmp / 28;
        int c = tmp2 % C2;
        int b = tmp2 / C2;
        float4 v = {0.f, 0.f, 0.f, 0.f};
        if (r >= 4 && r < 24 && c4 >= 1 && c4 <= 5)
            v = *(const float4*)(f2 + ((size_t)(b * TT + (TT - 1)) * C2 + c) * HW2 +
                                 (r - 4) * W2 + (c4 - 1) * 4);
        *(float4*)(pad + (size_t)id * 4) = v;
    } else {
        int i = (bid - 1792) * 256 + threadIdx.x;
        prep_frag_body(i, w0, w1, w2, g0, b0, m0, v0, g1, b1, m1, v1, g2, b2, m2, v2,
                       wb0, wb1, wb2, shift);
    }
}

// ---------------------------------------------------------------------------
// cost_lds_body: cost volume with XOR-swizzled LDS window tile.
// Per half (128 thr, 32 channels): stage only padded rows [dy, dy+20) of the
// 32-col cur tile (640 f, linear coalesced loads) into LDS with f4-slot
// swizzle phys = rr*8 + (slot ^ (rr&7)) -> conflict-free b128 reads.
// Double-buffered, 1 barrier/channel; past loads register-prefetched.
// ---------------------------------------------------------------------------
template <int NSPG>
static __device__ inline void cost_lds_body(int bi, const float* __restrict__ f2,
                                            const float* __restrict__ pad,
                                            float* __restrict__ Spart) {
    constexpr int CS = C2 / (NSPG * 2);   // 32 at NSPG=8
    __shared__ float tile[2][2][640];
    __shared__ float red[36][100];
    int cs = bi % NSPG;
    int rem = bi / NSPG;
    int dy = rem % 9; rem /= 9;
    int t = rem % 3;
    int b = rem / 3;
    int tid = threadIdx.x;
    int half = tid >> 7;
    int tl = tid & 127;
    bool act = (tl < 100);
    int qq = act ? tl : 0;
    int h = qq / 5;
    int w0 = (qq % 5) * 4;
    int p = h * W2 + w0;
    int c0 = cs * (2 * CS) + half * CS;

    const float* padbase = pad + ((size_t)(b * C2 + c0) * 28 + dy) * 32;
    const float* pp = f2 + ((size_t)(b * TT + t) * C2 + c0) * HW2 + p;

    float acc[36];
#pragma unroll
    for (int i = 0; i < 36; ++i) acc[i] = 0.f;

    // prologue: stage channel 0 into buf0, prefetch past ch0
    for (int s = tl; s < 160; s += 128) {
        int rr = s >> 3, sl = s & 7;
        float4 v = *(const float4*)(padbase + s * 4);
        *(float4*)&tile[half][0][(rr * 8 + (sl ^ (rr & 7))) * 4] = v;
    }
    float4 pv = {0.f, 0.f, 0.f, 0.f};
    if (act) pv = *(const float4*)(pp);
    __syncthreads();

    int j0 = w0 >> 2;
    int rx = h & 7;
    for (int c = 0; c < CS; ++c) {
        int buf = c & 1;
        if (c + 1 < CS) {
            const float* src = padbase + (size_t)(c + 1) * 28 * 32;
            for (int s = tl; s < 160; s += 128) {
                int rr = s >> 3, sl = s & 7;
                float4 v = *(const float4*)(src + s * 4);
                *(float4*)&tile[half][buf ^ 1][(rr * 8 + (sl ^ (rr & 7))) * 4] = v;
            }
        }
        float4 npv = pv;
        if (act) {
            if (c + 1 < CS) npv = *(const float4*)(pp + (size_t)(c + 1) * HW2);
            const float* tb = tile[half][buf];
            float4 ql = *(const float4*)&tb[(h * 8 + ((j0 + 0) ^ rx)) * 4];
            float4 qm = *(const float4*)&tb[(h * 8 + ((j0 + 1) ^ rx)) * 4];
            float4 qr = *(const float4*)&tb[(h * 8 + ((j0 + 2) ^ rx)) * 4];
            float cv[12] = {ql.x, ql.y, ql.z, ql.w,
                            qm.x, qm.y, qm.z, qm.w,
                            qr.x, qr.y, qr.z, qr.w};
#pragma unroll
            for (int dx = 0; dx < 9; ++dx) {
                acc[dx * 4 + 0] += fabsf(cv[dx + 0] - pv.x);
                acc[dx * 4 + 1] += fabsf(cv[dx + 1] - pv.y);
                acc[dx * 4 + 2] += fabsf(cv[dx + 2] - pv.z);
                acc[dx * 4 + 3] += fabsf(cv[dx + 3] - pv.w);
            }
        }
        pv = npv;
        __syncthreads();
    }

    if (half == 1 && act) {
#pragma unroll
        for (int i = 0; i < 36; ++i) red[i][qq] = acc[i];
    }
    __syncthreads();
    if (half == 0 && act) {
#pragma unroll
        for (int i = 0; i < 36; ++i) acc[i] += red[i][qq];
#pragma unroll
        for (int px = 0; px < 4; ++px) {
            float* dst = Spart + ((size_t)(cs * BB + b) * HW2 + (p + px)) * 336 +
                         t * 108 + dy * 12;
            float4 u0 = {-acc[0 + px], -acc[4 + px], -acc[8 + px], -acc[12 + px]};
            float4 u1 = {-acc[16 + px], -acc[20 + px], -acc[24 + px], -acc[28 + px]};
            float4 u2 = {-acc[32 + px], 0.f, 0.f, 0.f};
            *(float4*)(dst) = u0;
            *(float4*)(dst + 4) = u1;
            *(float4*)(dst + 8) = u2;
        }
    }
}

// ---------------------------------------------------------------------------
// pack_f body (R16/R17-validated): f-channel part of xpackT, sim slots zeroed.
// ---------------------------------------------------------------------------
template <int CI, int KP, int HW, int TILES>
static __device__ inline void pack_f_body(int cid, const float* __restrict__ f,
                                          unsigned short* __restrict__ xp) {
    constexpr int KB = KP / 32;
    int tid = threadIdx.x;
    int b = cid / (TILES * KB);
    int rem = cid % (TILES * KB);
    int tile = rem / KB;
    int ks = rem % KB;
    int px = tid >> 2;
    int p = tile * 64 + px;
    int c0 = ks * 32 + (tid & 3) * 8;
    bool pok = (p < HW);
    const float* fb = f + ((size_t)(b * TT + (TT - 1)) * CI) * HW + p;

    short8 o;
#pragma unroll
    for (int j = 0; j < 8; ++j) {
        int c = c0 + j;
        float v = 0.f;
        if (pok && c < CI) v = fb[(size_t)c * HW];
        o[j] = (short)f2bf(v);
    }
    ((short8*)(xp + ((size_t)(b * TILES + tile) * KB + ks) * 2048))[tid] = o;
}

// ---------------------------------------------------------------------------
// K_cost_packf: co-dispatch cost (LDS-tiled) with independent pack_f work.
// blocks [0,864): cost; [864,2864): L0 pack; [2864,3764): L1; [3764,4240): L2.
// ---------------------------------------------------------------------------
__global__ __launch_bounds__(256) void k_cost_packf(
    const float* __restrict__ f2, const float* __restrict__ pad,
    float* __restrict__ Spart,
    const float* __restrict__ f0, const float* __restrict__ f1,
    unsigned short* __restrict__ xp0, unsigned short* __restrict__ xp1,
    unsigned short* __restrict__ xp2) {
    int bid = blockIdx.x;
    if (bid < 864) {
        cost_lds_body<8>(bid, f2, pad, Spart);
    } else {
        int pb = bid - 864;
        if (pb < 2000) {
            pack_f_body<128, 160, 6400, 100>(pb, f0, xp0);
        } else if (pb < 2900) {
            pack_f_body<256, 288, 1600, 25>(pb - 2000, f1, xp1);
        } else {
            pack_f_body<512, 544, 400, 7>(pb - 2900, f2, xp2);
        }
    }
}

// ---------------------------------------------------------------------------
// bilinear sample of psim[b][400][4]; for HI=WI=20 degenerates to identity.
// ---------------------------------------------------------------------------
template <int HI, int WI>
static __device__ inline float bil(const float* __restrict__ psim, int b, int p, int ch) {
    int yi = p / WI, xi = p % WI;
    float cy = yi * (19.0f / (HI - 1));
    float cx = xi * (19.0f / (WI - 1));
    int y0 = (int)cy; if (y0 > 19) y0 = 19;
    int x0 = (int)cx; if (x0 > 19) x0 = 19;
    int y1 = min(y0 + 1, 19);
    int x1 = min(x0 + 1, 19);
    float wy = cy - y0, wx = cx - x0;
    const float* base = psim + (size_t)b * HW2 * 4;
    float v00 = base[(y0 * 20 + x0) * 4 + ch];
    float v01 = base[(y0 * 20 + x1) * 4 + ch];
    float v10 = base[(y1 * 20 + x0) * 4 + ch];
    float v11 = base[(y1 * 20 + x1) * 4 + ch];
    float r0 = v00 * (1.f - wy) + v10 * wy;
    float r1 = v01 * (1.f - wy) + v11 * wy;
    return r0 * (1.f - wx) + r1 * wx;
}

// ---------------------------------------------------------------------------
// K_pack_sim (R17-validated): write 4 bf16 sim channels into xpackT.
// ---------------------------------------------------------------------------
template <int CI, int KP, int HW, int TILES, int HI, int WI>
static __device__ inline void pack_sim_body(int id, const float* __restrict__ psim,
                                            unsigned short* __restrict__ xp) {
    constexpr int KB = KP / 32;
    constexpr int KS = CI / 32;
    int b = id / HW, p = id % HW;
    int tile = p / 64, px = p % 64;
    unsigned int lo = (unsigned int)f2bf(bil<HI, WI>(psim, b, p, 0)) |
                      ((unsigned int)f2bf(bil<HI, WI>(psim, b, p, 1)) << 16);
    unsigned int hi = (unsigned int)f2bf(bil<HI, WI>(psim, b, p, 2)) |
                      ((unsigned int)f2bf(bil<HI, WI>(psim, b, p, 3)) << 16);
    uint2 u = {lo, hi};
    *(uint2*)(xp + ((size_t)(b * TILES + tile) * KB + KS) * 2048 + px * 32) = u;
}

__global__ __launch_bounds__(256) void k_pack_sim(
    const float* __restrict__ psim,
    unsigned short* __restrict__ xp0, unsigned short* __restrict__ xp1,
    unsigned short* __restrict__ xp2) {
    int id = blockIdx.x * 256 + threadIdx.x;
    if (id < 25600) {
        pack_sim_body<128, 160, 6400, 100, 80, 80>(id, psim, xp0);
        return;
    }
    id -= 25600;
    if (id < 6400) {
        pack_sim_body<256, 288, 1600, 25, 40, 40>(id, psim, xp1);
        return;
    }
    id -= 6400;
    if (id < 1600)
        pack_sim_body<512, 544, 400, 7, 20, 20>(id, psim, xp2);
}

// ---------------------------------------------------------------------------
// K_cost LDS fallback (R6-validated, mode0)
// ---------------------------------------------------------------------------
template <int NSP, int TS>
__global__ __launch_bounds__(128) void k_cost(const float* __restrict__ f2,
                                              float* __restrict__ Spart) {
    constexpr int CS = C2 / NSP;
    __shared__ float curT[2][28][36];
    int bi = blockIdx.x;
    int cs = bi % NSP;
    int rem = bi / NSP;
    int dy = rem % 9; rem /= 9;
    int t = rem % 3;
    int b = rem / 3;
    int tid = threadIdx.x;
    bool act = (tid < 100);
    int q = act ? tid : 0;
    int h = q / 5;
    int w0 = (q % 5) * 4;
    int p = h * W2 + w0;

    const float* cur = f2 + ((size_t)(b * TT + (TT - 1)) * C2 + cs * CS) * HW2;
    const float* pst = f2 + ((size_t)(b * TT + t) * C2 + cs * CS) * HW2;

    for (int i = tid; i < 2 * 28 * 36; i += 128)
        ((float*)curT)[i] = 0.f;
    __syncthreads();

    float acc[36];
#pragma unroll
    for (int i = 0; i < 36; ++i) acc[i] = 0.f;

    if (act) {
        float4 v = *(const float4*)(cur + p);
        *(float4*)&curT[0][h + 4][w0 + 4] = v;
    }
    __syncthreads();

    for (int c = 0; c < CS; ++c) {
        int buf = c & 1;
        if (act) {
            if (c + 1 < CS) {
                float4 v = *(const float4*)(cur + (size_t)(c + 1) * HW2 + p);
                *(float4*)&curT[buf ^ 1][h + 4][w0 + 4] = v;
            }
            const float* base = &curT[buf][h + dy][w0];
            float4 ql = *(const float4*)(base);
            float4 qm = *(const float4*)(base + 4);
            float4 qr = *(const float4*)(base + 8);
            float4 pv = *(const float4*)(pst + (size_t)c * HW2 + p);
            float cv[12] = {ql.x, ql.y, ql.z, ql.w,
                            qm.x, qm.y, qm.z, qm.w,
                            qr.x, qr.y, qr.z, qr.w};
#pragma unroll
            for (int dx = 0; dx < 9; ++dx) {
                acc[dx * 4 + 0] += fabsf(cv[dx + 0] - pv.x);
                acc[dx * 4 + 1] += fabsf(cv[dx + 1] - pv.y);
                acc[dx * 4 + 2] += fabsf(cv[dx + 2] - pv.z);
                acc[dx * 4 + 3] += fabsf(cv[dx + 3] - pv.w);
            }
        }
        __syncthreads();
    }

    if (act) {
        int tsbase = t * NS + dy * KK;
#pragma unroll
        for (int px = 0; px < 4; ++px) {
            float* dst = Spart + ((size_t)(cs * BB + b) * HW2 + (p + px)) * TS + tsbase;
#pragma unroll
            for (int dx = 0; dx < 9; ++dx) dst[dx] = -acc[dx * 4 + px];
        }
    }
}

// ---------------------------------------------------------------------------
// K_smax_conv1 (validated): NSP partials, TS stride, P12 index map
// ---------------------------------------------------------------------------
template <int NSP, int TS, bool P12>
__global__ __launch_bounds__(256) void k_smax_conv1(
    const float* __restrict__ Spart, const float* __restrict__ w1,
    const float* __restrict__ g1, const float* __restrict__ b1,
    const float* __restrict__ m1, const float* __restrict__ v1,
    float* __restrict__ psim) {
    __shared__ float sS[NTS];
    __shared__ float sP[NTS];
    int bp = blockIdx.x;
    int tid = threadIdx.x;
    if (tid < NTS) {
        int idx;
        if (P12) {
            int t = tid / 81, r = tid % 81;
            idx = t * 108 + (r / 9) * 12 + (r % 9);
        } else {
            idx = tid;
        }
        float S = 0.f;
#pragma unroll
        for (int k = 0; k < NSP; ++k)
            S += Spart[((size_t)(k * BB * HW2) + bp) * TS + idx];
        sS[tid] = S;
    }
    __syncthreads();
    int wave = tid >> 6, lane = tid & 63;
    if (wave < NT) {
        int base = wave * NS;
        float v0 = sS[base + lane];
        float vo = (lane < NS - 64) ? sS[base + 64 + lane] : -1e30f;
        float m = fmaxf(v0, vo);
#pragma unroll
        for (int off = 32; off; off >>= 1) m = fmaxf(m, __shfl_xor(m, off));
        float e0 = __expf(v0 - m);
        float e1 = (lane < NS - 64) ? __expf(vo - m) : 0.f;
        float s = e0 + e1;
#pragma unroll
        for (int off = 32; off; off >>= 1) s += __shfl_xor(s, off);
        float inv = 1.f / s;
        sP[base + lane] = e0 * inv;
        if (lane < NS - 64) sP[base + 64 + lane] = e1 * inv;
    }
    __syncthreads();
    if (tid < 64) {
        int o = tid >> 4, j = tid & 15;
        float acc = 0.f;
#pragma unroll
        for (int mm = 0; mm < 16; ++mm) {
            int k = j + (mm << 4);
            if (k < NTS) acc += w1[o * NTS + k] * sP[k];
        }
#pragma unroll
        for (int off = 8; off; off >>= 1) acc += __shfl_xor(acc, off);
        if (j == 0) {
            float sc = g1[o] * rsqrtf(v1[o] + EPSBN);
            float y = (acc - m1[o]) * sc + b1[o];
            float sig = 1.f / (1.f + __expf(-y));
            psim[(size_t)bp * HID + o] = y * sig;
        }
    }
}

// ---------------------------------------------------------------------------
// K_resize (fallback path only)
// ---------------------------------------------------------------------------
__global__ void k_resize(const float* __restrict__ psim, float* __restrict__ pre0,
                         float* __restrict__ pre1) {
    int id = blockIdx.x * 256 + threadIdx.x;
    int Hi, Wi, bb2, pp;
    float* dst;
    if (id < BB * 6400) {
        Hi = 80; Wi = 80; bb2 = id / 6400; pp = id % 6400; dst = pre0 + (size_t)id * 4;
    } else {
        id -= BB * 6400;
        if (id >= BB * 1600) return;
        Hi = 40; Wi = 40; bb2 = id / 1600; pp = id % 1600; dst = pre1 + (size_t)id * 4;
    }
    int yi = pp / Wi, xi = pp % Wi;
    float cy = yi * (19.0f / (Hi - 1));
    float cx = xi * (19.0f / (Wi - 1));
    int y0 = (int)cy; if (y0 > 19) y0 = 19;
    int x0 = (int)cx; if (x0 > 19) x0 = 19;
    int y1 = min(y0 + 1, 19);
    int x1 = min(x0 + 1, 19);
    float wy = cy - y0, wx = cx - x0;
    const float4* base = (const float4*)psim + (size_t)bb2 * HW2;
    float4 v00 = base[y0 * 20 + x0];
    float4 v01 = base[y0 * 20 + x1];
    float4 v10 = base[y1 * 20 + x0];
    float4 v11 = base[y1 * 20 + x1];
    float4 r0, r1, o4;
    r0.x = v00.x * (1.f - wy) + v10.x * wy; r0.y = v00.y * (1.f - wy) + v10.y * wy;
    r0.z = v00.z * (1.f - wy) + v10.z * wy; r0.w = v00.w * (1.f - wy) + v10.w * wy;
    r1.x = v01.x * (1.f - wy) + v11.x * wy; r1.y = v01.y * (1.f - wy) + v11.y * wy;
    r1.z = v01.z * (1.f - wy) + v11.z * wy; r1.w = v01.w * (1.f - wy) + v11.w * wy;
    o4.x = r0.x * (1.f - wx) + r1.x * wx; o4.y = r0.y * (1.f - wx) + r1.y * wx;
    o4.z = r0.z * (1.f - wx) + r1.z * wx; o4.w = r0.w * (1.f - wx) + r1.w * wx;
    *(float4*)dst = o4;
}

// ---------------------------------------------------------------------------
// gemmP body (R15/R16-validated): dbuf MFMA loop + LDS-transposed f4 epilogue
// ---------------------------------------------------------------------------
template <int O, int KP, int HW, int TILES>
static __device__ inline void gemmP_body(int lbid, const unsigned short* __restrict__ xp,
                                         const unsigned short* __restrict__ wbF,
                                         const float* __restrict__ shift,
                                         float* __restrict__ out,
                                         unsigned short* __restrict__ xls,
                                         float* __restrict__ cls_all) {
    constexpr int OB = O / 64;
    constexpr int KB = KP / 32;

    int tid = threadIdx.x;
    int lane = tid & 63, wv = tid >> 6;
    int ob = lbid % OB;
    int rest = lbid / OB;
    int b = rest / TILES;
    int tile = rest % TILES;
    int p0 = tile * 64;

    int l15 = lane & 15, lhi = lane >> 4;
    int o_w = ob * 64 + (wv & 1) * 32;
    int pw_loc = (wv >> 1) * 32;

    int o16 = o_w >> 4;
    const short8* a0p = (const short8*)wbF + ((size_t)o16 * KB) * 64 + lane;
    const short8* a1p = a0p + (size_t)KB * 64;
    const short8* chunk = (const short8*)(xp + ((size_t)(b * TILES + tile) * KB) * 2048);

    floatx4 acc00 = {0.f, 0.f, 0.f, 0.f}, acc01 = acc00, acc10 = acc00, acc11 = acc00;

    short8 v = chunk[tid];
    ((short8*)xls)[tid] = v;
    if (KB > 1) v = chunk[256 + tid];
    __syncthreads();

    for (int ks = 0; ks < KB; ++ks) {
        const unsigned short* buf = xls + (ks & 1) * 2048;
        short8 cb0 = *(const short8*)&buf[(pw_loc + l15) * 32 + lhi * 8];
        short8 cb1 = *(const short8*)&buf[(pw_loc + 16 + l15) * 32 + lhi * 8];
        if (ks + 1 < KB) {
            ((short8*)(xls + ((ks + 1) & 1) * 2048))[tid] = v;
            if (ks + 2 < KB) v = chunk[(ks + 2) * 256 + tid];
        }
        short8 ca0 = a0p[ks * 64];
        short8 ca1 = a1p[ks * 64];
        acc00 = __builtin_amdgcn_mfma_f32_16x16x32_bf16(ca0, cb0, acc00, 0, 0, 0);
        acc01 = __builtin_amdgcn_mfma_f32_16x16x32_bf16(ca0, cb1, acc01, 0, 0, 0);
        acc10 = __builtin_amdgcn_mfma_f32_16x16x32_bf16(ca1, cb0, acc10, 0, 0, 0);
        acc11 = __builtin_amdgcn_mfma_f32_16x16x32_bf16(ca1, cb1, acc11, 0, 0, 0);
        __syncthreads();
    }

    float* cls = cls_all + wv * (32 * 36);
#pragma unroll
    for (int osub = 0; osub < 2; ++osub) {
#pragma unroll
        for (int psub = 0; psub < 2; ++psub) {
            floatx4 d = osub ? (psub ? acc11 : acc10) : (psub ? acc01 : acc00);
#pragma unroll
            for (int r = 0; r < 4; ++r)
                cls[(osub * 16 + lhi * 4 + r) * 36 + psub * 16 + l15] = d[r];
        }
    }
#pragma unroll
    for (int i = 0; i < 4; ++i) {
        int o_loc = (lane >> 3) + i * 8;
        int pq = (lane & 7) * 4;
        int p = p0 + pw_loc + pq;
        if (p < HW) {
            float4 vv = *(float4*)&cls[o_loc * 36 + pq];
            int o = o_w + o_loc;
            float sh = shift[o];
            float4 so;
            float y;
            y = vv.x + sh; so.x = y / (1.f + __expf(-y));
            y = vv.y + sh; so.y = y / (1.f + __expf(-y));
            y = vv.z + sh; so.z = y / (1.f + __expf(-y));
            y = vv.w + sh; so.w = y / (1.f + __expf(-y));
            *(float4*)&out[((size_t)b * O + o) * HW + p] = so;
        }
    }
}

// merged gemm: L0 [0,800), L1 [800,1200), L2 [1200,1424)
__global__ __launch_bounds__(256) void k_gemmP_all(
    const unsigned short* __restrict__ xp0, const unsigned short* __restrict__ xp1,
    const unsigned short* __restrict__ xp2,
    const unsigned short* __restrict__ wb0, const unsigned short* __restrict__ wb1,
    const unsigned short* __restrict__ wb2,
    const float* __restrict__ shift, float* __restrict__ out) {
    __shared__ unsigned short xls[4096];
    __shared__ float cls[4 * 32 * 36];
    int bid = blockIdx.x;
    if (bid < 800) {
        gemmP_body<128, 160, 6400, 100>(bid, xp0, wb0, shift, out, xls, cls);
    } else if (bid < 1200) {
        gemmP_body<256, 288, 1600, 25>(bid - 800, xp1, wb1, shift + 128,
                                       out + 3276800, xls, cls);
    } else {
        gemmP_body<512, 544, 400, 7>(bid - 1200, xp2, wb2, shift + 384,
                                     out + 3276800 + 1638400, xls, cls);
    }
}

// ---------------------------------------------------------------------------
// K_gemm fused fallback (R3-validated, mode0 only; linear wb layout)
// ---------------------------------------------------------------------------
#define XLS_STRIDE 40
template <int O, int KP, int K, int HW, int TILES>
__global__ __launch_bounds__(256) void k_gemm(
    const float* __restrict__ f, const float* __restrict__ pre,
    const unsigned short* __restrict__ wb, const float* __restrict__ shift,
    float* __restrict__ out) {
    constexpr int CI = O;
    constexpr int OB = O / 64;
    __shared__ unsigned short xlsf[64 * XLS_STRIDE];

    int tid = threadIdx.x;
    int lane = tid & 63, wv = tid >> 6;
    int ob = blockIdx.x % OB;
    int rest = blockIdx.x / OB;
    int b = rest / TILES;
    int p0 = (rest % TILES) * 64;

    int l15 = lane & 15, lhi = lane >> 4;
    int o_w = ob * 64 + (wv & 1) * 32;
    int pw_loc = (wv >> 1) * 32;

    int c_l = tid >> 3;
    int pq = (tid & 7) * 8;
    const float* fbase = f + ((size_t)(b * TT + (TT - 1)) * CI) * HW;
    const float* pbase = pre + (size_t)b * HW * 4;

    const short8* aptr0 = (const short8*)(wb + (size_t)(o_w + l15) * KP + lhi * 8);
    const short8* aptr1 = (const short8*)(wb + (size_t)(o_w + 16 + l15) * KP + lhi * 8);

    floatx4 acc00 = {0.f, 0.f, 0.f, 0.f}, acc01 = acc00, acc10 = acc00, acc11 = acc00;

    for (int c0 = 0; c0 < KP; c0 += 32) {
        __syncthreads();
        {
            int c = c0 + c_l;
            float vals[8];
            if (c < CI) {
                const float* src = fbase + (size_t)c * HW + p0 + pq;
                if (p0 + pq + 7 < HW) {
                    float4 a = ((const float4*)src)[0];
                    float4 bq = ((const float4*)src)[1];
                    vals[0] = a.x; vals[1] = a.y; vals[2] = a.z; vals[3] = a.w;
                    vals[4] = bq.x; vals[5] = bq.y; vals[6] = bq.z; vals[7] = bq.w;
                } else {
#pragma unroll
                    for (int i = 0; i < 8; ++i) {
                        int p = p0 + pq + i;
                        vals[i] = (p < HW) ? src[i] : 0.f;
                    }
                }
            } else if (c < K) {
#pragma unroll
                for (int i = 0; i < 8; ++i) {
                    int p = p0 + pq + i;
                    vals[i] = (p < HW) ? pbase[(size_t)p * 4 + (c - CI)] : 0.f;
                }
            } else {
#pragma unroll
                for (int i = 0; i < 8; ++i) vals[i] = 0.f;
            }
#pragma unroll
            for (int i = 0; i < 8; ++i)
                xlsf[(pq + i) * XLS_STRIDE + c_l] = f2bf(vals[i]);
        }
        __syncthreads();

        short8 ca0 = aptr0[c0 >> 3];
        short8 ca1 = aptr1[c0 >> 3];
        short8 cb0 = *(const short8*)&xlsf[(pw_loc + l15) * XLS_STRIDE + lhi * 8];
        short8 cb1 = *(const short8*)&xlsf[(pw_loc + 16 + l15) * XLS_STRIDE + lhi * 8];
        acc00 = __builtin_amdgcn_mfma_f32_16x16x32_bf16(ca0, cb0, acc00, 0, 0, 0);
        acc01 = __builtin_amdgcn_mfma_f32_16x16x32_bf16(ca0, cb1, acc01, 0, 0, 0);
        acc10 = __builtin_amdgcn_mfma_f32_16x16x32_bf16(ca1, cb0, acc10, 0, 0, 0);
        acc11 = __builtin_amdgcn_mfma_f32_16x16x32_bf16(ca1, cb1, acc11, 0, 0, 0);
    }

#pragma unroll
    for (int osub = 0; osub < 2; ++osub) {
#pragma unroll
        for (int psub = 0; psub < 2; ++psub) {
            floatx4 d = osub ? (psub ? acc11 : acc10) : (psub ? acc01 : acc00);
            int p = p0 + pw_loc + psub * 16 + l15;
            int obase = o_w + osub * 16 + lhi * 4;
            if (p < HW) {
#pragma unroll
                for (int r = 0; r < 4; ++r) {
                    int o = obase + r;
                    float y = d[r] + shift[o];
                    float sig = 1.f / (1.f + __expf(-y));
                    out[((size_t)b * O + o) * HW + p] = y * sig;
                }
            }
        }
    }
}

// ---------------------------------------------------------------------------
extern "C" void kernel_launch(void* const* d_in, const int* in_sizes, int n_in,
                              void* d_out, int out_size, void* d_ws, size_t ws_size,
                              hipStream_t stream) {
    const float* f0 = (const float*)d_in[0];
    const float* f1 = (const float*)d_in[1];
    const float* f2 = (const float*)d_in[2];
    const float* w1 = (const float*)d_in[5];
    const float* g1 = (const float*)d_in[6];
    const float* b1 = (const float*)d_in[7];
    const float* m1 = (const float*)d_in[8];
    const float* v1 = (const float*)d_in[9];
    const float* w2_0 = (const float*)d_in[10];
    const float* g2_0 = (const float*)d_in[11];
    const float* b2_0 = (const float*)d_in[12];
    const float* m2_0 = (const float*)d_in[13];
    const float* v2_0 = (const float*)d_in[14];
    const float* w2_1 = (const float*)d_in[15];
    const float* g2_1 = (const float*)d_in[16];
    const float* b2_1 = (const float*)d_in[17];
    const float* m2_1 = (const float*)d_in[18];
    const float* v2_1 = (const float*)d_in[19];
    const float* w2_2 = (const float*)d_in[20];
    const float* g2_2 = (const float*)d_in[21];
    const float* b2_2 = (const float*)d_in[22];
    const float* m2_2 = (const float*)d_in[23];
    const float* v2_2 = (const float*)d_in[24];

    float* ws = (float*)d_ws;
    const size_t PADSZ = (size_t)BB * C2 * 28 * 32;          // 1,835,008 fl
    const size_t SP336_8 = (size_t)8 * BB * HW2 * 336;       // 4,300,800 fl
    const size_t SP8 = (size_t)8 * BB * HW2 * 256;           // 3,276,800 fl
    const size_t XP0 = 2048000, XP1 = 921600, XP2 = 487424;  // floats
    const size_t need2 =
        (SP336_8 + PADSZ + 6400 + 10240 + 36864 + 139264 + 896 + XP0 + XP1 + XP2) * 4;
    int mode = (ws_size >= need2) ? 2 : 0;

    float* out = (float*)d_out;

    if (mode == 2) {
        float* Spart = ws;
        float* pad = ws + SP336_8;
        float* psim = pad + PADSZ;
        unsigned short* wb0 = (unsigned short*)(psim + 6400);
        unsigned short* wb1 = wb0 + 20480;
        unsigned short* wb2 = wb1 + 73728;
        float* shift = (float*)(wb2 + 278528);
        float* xb = shift + 896;
        unsigned short* xp0 = (unsigned short*)xb;
        unsigned short* xp1 = (unsigned short*)(xb + XP0);
        unsigned short* xp2 = (unsigned short*)(xb + XP0 + XP1);

        k_prep_pad<<<dim3(3252), dim3(256), 0, stream>>>(
            f2, pad,
            w2_0, w2_1, w2_2,
            g2_0, b2_0, m2_0, v2_0,
            g2_1, b2_1, m2_1, v2_1,
            g2_2, b2_2, m2_2, v2_2,
            wb0, wb1, wb2, shift);
        k_cost_packf<<<dim3(4240), dim3(256), 0, stream>>>(
            f2, pad, Spart, f0, f1, xp0, xp1, xp2);
        k_smax_conv1<8, 336, true><<<dim3(1600), dim3(256), 0, stream>>>(
            Spart, w1, g1, b1, m1, v1, psim);
        k_pack_sim<<<dim3(132), dim3(256), 0, stream>>>(psim, xp0, xp1, xp2);
        k_gemmP_all<<<dim3(1424), dim3(256), 0, stream>>>(
            xp0, xp1, xp2, wb0, wb1, wb2, shift, out);
    } else {
        float* Spart = ws;
        float* psim = ws + SP8;
        float* pre0 = psim + 6400;
        float* pre1 = pre0 + 102400;
        unsigned short* wb0 = (unsigned short*)(pre1 + 25600);
        unsigned short* wb1 = wb0 + 20480;
        unsigned short* wb2 = wb1 + 73728;
        float* shift = (float*)(wb2 + 278528);

        k_prep<<<dim3(1460), dim3(256), 0, stream>>>(
            w2_0, w2_1, w2_2,
            g2_0, b2_0, m2_0, v2_0,
            g2_1, b2_1, m2_1, v2_1,
            g2_2, b2_2, m2_2, v2_2,
            wb0, wb1, wb2, shift);
        k_cost<8, 256><<<dim3(8 * 108), dim3(128), 0, stream>>>(f2, Spart);
        k_smax_conv1<8, 256, false><<<dim3(1600), dim3(256), 0, stream>>>(
            Spart, w1, g1, b1, m1, v1, psim);
        k_resize<<<dim3(125), dim3(256), 0, stream>>>(psim, pre0, pre1);
        k_gemm<128, 160, 132, 6400, 100><<<dim3(800), dim3(256), 0, stream>>>(
            f0, pre0, wb0, shift, out);
        k_gemm<256, 288, 260, 1600, 25><<<dim3(400), dim3(256), 0, stream>>>(
            f1, pre1, wb1, shift + 128, out + 3276800);
        k_gemm<512, 544, 516, 400, 7><<<dim3(224), dim3(256), 0, stream>>>(
            f2, psim, wb2, shift + 384, out + 3276800 + 1638400);
    }
}

// Round 19
// 62.424 us; speedup vs baseline: 1.1390x; 1.1390x over previous
//
#include <hip/hip_runtime.h>
#include <math.h>

#define EPSBN 1e-3f

// geometry
#define BB 4
#define TT 4
#define C2 512
#define H2 20
#define W2 20
#define HW2 400
#define RR 4
#define KK 9
#define NS 81
#define NT 3
#define NTS 243
#define HID 4

typedef __attribute__((ext_vector_type(8))) short short8;
typedef __attribute__((ext_vector_type(4))) float floatx4;

static __device__ inline unsigned short f2bf(float f) {
    unsigned int u = __float_as_uint(f);
    unsigned int r = (u + 0x7fffu + ((u >> 16) & 1u)) >> 16;
    return (unsigned short)r;
}

// ---------------------------------------------------------------------------
// prep_frag: conv2 weights -> bf16 MFMA-fragment layout (R12/R13-validated)
// ---------------------------------------------------------------------------
static __device__ inline void prep_frag_body(
    int i,
    const float* __restrict__ w0, const float* __restrict__ w1,
    const float* __restrict__ w2,
    const float* __restrict__ g0, const float* __restrict__ b0,
    const float* __restrict__ m0, const float* __restrict__ v0,
    const float* __restrict__ g1, const float* __restrict__ b1,
    const float* __restrict__ m1, const float* __restrict__ v1,
    const float* __restrict__ g2, const float* __restrict__ b2,
    const float* __restrict__ m2, const float* __restrict__ v2,
    unsigned short* __restrict__ wb0, unsigned short* __restrict__ wb1,
    unsigned short* __restrict__ wb2, float* __restrict__ shift) {
    if (i < 20480) {  // L0: KB=5
        int j = i & 7, lane = (i >> 3) & 63;
        int blk = i >> 9;
        int kb = blk % 5, o16 = blk / 5;
        int o = o16 * 16 + (lane & 15);
        int k = kb * 32 + (lane >> 4) * 8 + j;
        float sc = g0[o] * rsqrtf(v0[o] + EPSBN);
        wb0[i] = f2bf(k < 132 ? w0[o * 132 + k] * sc : 0.f);
        return;
    }
    i -= 20480;
    if (i < 73728) {  // L1: KB=9
        int j = i & 7, lane = (i >> 3) & 63;
        int blk = i >> 9;
        int kb = blk % 9, o16 = blk / 9;
        int o = o16 * 16 + (lane & 15);
        int k = kb * 32 + (lane >> 4) * 8 + j;
        float sc = g1[o] * rsqrtf(v1[o] + EPSBN);
        wb1[i] = f2bf(k < 260 ? w1[o * 260 + k] * sc : 0.f);
        return;
    }
    i -= 73728;
    if (i < 278528) {  // L2: KB=17
        int j = i & 7, lane = (i >> 3) & 63;
        int blk = i >> 9;
        int kb = blk % 17, o16 = blk / 17;
        int o = o16 * 16 + (lane & 15);
        int k = kb * 32 + (lane >> 4) * 8 + j;
        float sc = g2[o] * rsqrtf(v2[o] + EPSBN);
        wb2[i] = f2bf(k < 516 ? w2[o * 516 + k] * sc : 0.f);
        return;
    }
    i -= 278528;
    if (i < 896) {
        if (i < 128) {
            float sc = g0[i] * rsqrtf(v0[i] + EPSBN);
            shift[i] = b0[i] - m0[i] * sc;
        } else if (i < 384) {
            int o = i - 128;
            float sc = g1[o] * rsqrtf(v1[o] + EPSBN);
            shift[i] = b1[o] - m1[o] * sc;
        } else {
            int o = i - 384;
            float sc = g2[o] * rsqrtf(v2[o] + EPSBN);
            shift[i] = b2[o] - m2[o] * sc;
        }
    }
}

// linear prep (fallback path, R1-validated)
static __device__ inline void prep_body(
    int i,
    const float* __restrict__ w0, const float* __restrict__ w1,
    const float* __restrict__ w2,
    const float* __restrict__ g0, const float* __restrict__ b0,
    const float* __restrict__ m0, const float* __restrict__ v0,
    const float* __restrict__ g1, const float* __restrict__ b1,
    const float* __restrict__ m1, const float* __restrict__ v1,
    const float* __restrict__ g2, const float* __restrict__ b2,
    const float* __restrict__ m2, const float* __restrict__ v2,
    unsigned short* __restrict__ wb0, unsigned short* __restrict__ wb1,
    unsigned short* __restrict__ wb2, float* __restrict__ shift) {
    if (i < 128 * 160) {
        int o = i / 160, k = i % 160;
        float sc = g0[o] * rsqrtf(v0[o] + EPSBN);
        wb0[i] = f2bf(k < 132 ? w0[o * 132 + k] * sc : 0.f);
        return;
    }
    i -= 128 * 160;
    if (i < 256 * 288) {
        int o = i / 288, k = i % 288;
        float sc = g1[o] * rsqrtf(v1[o] + EPSBN);
        wb1[i] = f2bf(k < 260 ? w1[o * 260 + k] * sc : 0.f);
        return;
    }
    i -= 256 * 288;
    if (i < 512 * 544) {
        int o = i / 544, k = i % 544;
        float sc = g2[o] * rsqrtf(v2[o] + EPSBN);
        wb2[i] = f2bf(k < 516 ? w2[o * 516 + k] * sc : 0.f);
        return;
    }
    i -= 512 * 544;
    if (i < 896) {
        if (i < 128) {
            float sc = g0[i] * rsqrtf(v0[i] + EPSBN);
            shift[i] = b0[i] - m0[i] * sc;
        } else if (i < 384) {
            int o = i - 128;
            float sc = g1[o] * rsqrtf(v1[o] + EPSBN);
            shift[i] = b1[o] - m1[o] * sc;
        } else {
            int o = i - 384;
            float sc = g2[o] * rsqrtf(v2[o] + EPSBN);
            shift[i] = b2[o] - m2[o] * sc;
        }
    }
}

__global__ void k_prep(const float* w0, const float* w1, const float* w2,
                       const float* g0, const float* b0, const float* m0, const float* v0,
                       const float* g1, const float* b1, const float* m1, const float* v1,
                       const float* g2, const float* b2, const float* m2, const float* v2,
                       unsigned short* wb0, unsigned short* wb1,
                       unsigned short* wb2, float* shift) {
    int i = blockIdx.x * 256 + threadIdx.x;
    prep_body(i, w0, w1, w2, g0, b0, m0, v0, g1, b1, m1, v1, g2, b2, m2, v2,
              wb0, wb1, wb2, shift);
}

// ---------------------------------------------------------------------------
// K_prep_pad: fused fragment-prep + zero-padded last-frame copy (R13-validated)
// ---------------------------------------------------------------------------
__global__ void k_prep_pad(const float* __restrict__ f2, float* __restrict__ pad,
                           const float* w0, const float* w1, const float* w2,
                           const float* g0, const float* b0, const float* m0, const float* v0,
                           const float* g1, const float* b1, const float* m1, const float* v1,
                           const float* g2, const float* b2, const float* m2, const float* v2,
                           unsigned short* wb0, unsigned short* wb1,
                           unsigned short* wb2, float* shift) {
    int bid = blockIdx.x;
    if (bid < 1792) {
        int id = bid * 256 + threadIdx.x;           // float4 index
        if (id >= BB * C2 * 28 * 8) return;
        int c4 = id & 7;
        int tmp = id >> 3;
        int r = tmp % 28;
        int tmp2 = tmp / 28;
        int c = tmp2 % C2;
        int b = tmp2 / C2;
        float4 v = {0.f, 0.f, 0.f, 0.f};
        if (r >= 4 && r < 24 && c4 >= 1 && c4 <= 5)
            v = *(const float4*)(f2 + ((size_t)(b * TT + (TT - 1)) * C2 + c) * HW2 +
                                 (r - 4) * W2 + (c4 - 1) * 4);
        *(float4*)(pad + (size_t)id * 4) = v;
    } else {
        int i = (bid - 1792) * 256 + threadIdx.x;
        prep_frag_body(i, w0, w1, w2, g0, b0, m0, v0, g1, b1, m1, v1, g2, b2, m2, v2,
                       wb0, wb1, wb2, shift);
    }
}

// ---------------------------------------------------------------------------
// cost_cs body v3: register path (R17) with SHUFFLE-SHARED window quads.
// Row-aligned lane map (rows never cross a wave): wave0 lanes 0..59 = rows
// 0..11, wave1 lanes 0..39 = rows 12..19. Each lane loads ONLY its mid quad
// (pad cols w0+4..w0+7) + past quad; ql/qr come from __shfl_up/down(mid,1),
// row-edge lanes masked to the pad halo's zeros. 2 VMEM/ch instead of 4.
// ---------------------------------------------------------------------------
template <int NSPG>
static __device__ inline void cost_cs_body(int bi, const float* __restrict__ f2,
                                           const float* __restrict__ pad,
                                           float* __restrict__ Spart) {
    constexpr int CS = C2 / (NSPG * 2);
    __shared__ float red[36][100];
    int cs = bi % NSPG;
    int rem = bi / NSPG;
    int dy = rem % 9; rem /= 9;
    int t = rem % 3;
    int b = rem / 3;
    int tid = threadIdx.x;
    int half = tid >> 7;
    int tl = tid & 127;
    int hw = tl >> 6;            // wave within half
    int lane = tl & 63;
    int hrow = lane / 5, r5 = lane - hrow * 5;
    bool act = hw == 0 ? (lane < 60) : (lane < 40);
    int h = hw == 0 ? hrow : 12 + hrow;
    if (!act) { h = 0; r5 = 0; }
    int w0 = r5 * 4;
    int q = h * 5 + r5;          // 0..99 linear pixel-quad id
    int p = h * W2 + w0;
    int c0 = cs * (2 * CS) + half * CS;

    const float* pm = pad + ((size_t)(b * C2 + c0) * 28 + (h + dy)) * 32 + w0 + 4;
    const float* pp = f2 + ((size_t)(b * TT + t) * C2 + c0) * HW2 + p;

    float acc[36];
#pragma unroll
    for (int i = 0; i < 36; ++i) acc[i] = 0.f;

    float4 mid = {0.f, 0.f, 0.f, 0.f}, pv = {0.f, 0.f, 0.f, 0.f};
    if (act) {
        mid = *(const float4*)(pm);
        pv = *(const float4*)(pp);
    }
    for (int c = 0; c < CS; ++c) {
        float4 nmid = mid, npv = pv;
        if (act && c + 1 < CS) {
            pm += 28 * 32;
            pp += HW2;
            nmid = *(const float4*)(pm);
            npv = *(const float4*)(pp);
        }
        // window neighbors via intra-wave shuffles (all lanes participate)
        float4 ql, qr;
        ql.x = __shfl_up(mid.x, 1); ql.y = __shfl_up(mid.y, 1);
        ql.z = __shfl_up(mid.z, 1); ql.w = __shfl_up(mid.w, 1);
        qr.x = __shfl_down(mid.x, 1); qr.y = __shfl_down(mid.y, 1);
        qr.z = __shfl_down(mid.z, 1); qr.w = __shfl_down(mid.w, 1);
        if (act) {
            if (r5 == 0) { ql.x = 0.f; ql.y = 0.f; ql.z = 0.f; ql.w = 0.f; }
            if (r5 == 4) { qr.x = 0.f; qr.y = 0.f; qr.z = 0.f; qr.w = 0.f; }
            float cv[12] = {ql.x, ql.y, ql.z, ql.w,
                            mid.x, mid.y, mid.z, mid.w,
                            qr.x, qr.y, qr.z, qr.w};
#pragma unroll
            for (int dx = 0; dx < 9; ++dx) {
                acc[dx * 4 + 0] += fabsf(cv[dx + 0] - pv.x);
                acc[dx * 4 + 1] += fabsf(cv[dx + 1] - pv.y);
                acc[dx * 4 + 2] += fabsf(cv[dx + 2] - pv.z);
                acc[dx * 4 + 3] += fabsf(cv[dx + 3] - pv.w);
            }
        }
        mid = nmid; pv = npv;
    }

    if (half == 1 && act) {
#pragma unroll
        for (int i = 0; i < 36; ++i) red[i][q] = acc[i];
    }
    __syncthreads();
    if (half == 0 && act) {
#pragma unroll
        for (int i = 0; i < 36; ++i) acc[i] += red[i][q];
#pragma unroll
        for (int px = 0; px < 4; ++px) {
            float* dst = Spart + ((size_t)(cs * BB + b) * HW2 + (p + px)) * 336 +
                         t * 108 + dy * 12;
            float4 u0 = {-acc[0 + px], -acc[4 + px], -acc[8 + px], -acc[12 + px]};
            float4 u1 = {-acc[16 + px], -acc[20 + px], -acc[24 + px], -acc[28 + px]};
            float4 u2 = {-acc[32 + px], 0.f, 0.f, 0.f};
            *(float4*)(dst) = u0;
            *(float4*)(dst + 4) = u1;
            *(float4*)(dst + 8) = u2;
        }
    }
}

// ---------------------------------------------------------------------------
// pack_f body (R16/R17-validated): f-channel part of xpackT, sim slots zeroed.
// ---------------------------------------------------------------------------
template <int CI, int KP, int HW, int TILES>
static __device__ inline void pack_f_body(int cid, const float* __restrict__ f,
                                          unsigned short* __restrict__ xp) {
    constexpr int KB = KP / 32;
    int tid = threadIdx.x;
    int b = cid / (TILES * KB);
    int rem = cid % (TILES * KB);
    int tile = rem / KB;
    int ks = rem % KB;
    int px = tid >> 2;
    int p = tile * 64 + px;
    int c0 = ks * 32 + (tid & 3) * 8;
    bool pok = (p < HW);
    const float* fb = f + ((size_t)(b * TT + (TT - 1)) * CI) * HW + p;

    short8 o;
#pragma unroll
    for (int j = 0; j < 8; ++j) {
        int c = c0 + j;
        float v = 0.f;
        if (pok && c < CI) v = fb[(size_t)c * HW];
        o[j] = (short)f2bf(v);
    }
    ((short8*)(xp + ((size_t)(b * TILES + tile) * KB + ks) * 2048))[tid] = o;
}

// ---------------------------------------------------------------------------
// K_cost_packf: co-dispatch cost (register+shuffle) with independent pack_f.
// blocks [0,864): cost; [864,2864): L0 pack; [2864,3764): L1; [3764,4240): L2.
// ---------------------------------------------------------------------------
__global__ __launch_bounds__(256) void k_cost_packf(
    const float* __restrict__ f2, const float* __restrict__ pad,
    float* __restrict__ Spart,
    const float* __restrict__ f0, const float* __restrict__ f1,
    unsigned short* __restrict__ xp0, unsigned short* __restrict__ xp1,
    unsigned short* __restrict__ xp2) {
    int bid = blockIdx.x;
    if (bid < 864) {
        cost_cs_body<8>(bid, f2, pad, Spart);
    } else {
        int pb = bid - 864;
        if (pb < 2000) {
            pack_f_body<128, 160, 6400, 100>(pb, f0, xp0);
        } else if (pb < 2900) {
            pack_f_body<256, 288, 1600, 25>(pb - 2000, f1, xp1);
        } else {
            pack_f_body<512, 544, 400, 7>(pb - 2900, f2, xp2);
        }
    }
}

// ---------------------------------------------------------------------------
// bilinear sample of psim[b][400][4]; for HI=WI=20 degenerates to identity.
// ---------------------------------------------------------------------------
template <int HI, int WI>
static __device__ inline float bil(const float* __restrict__ psim, int b, int p, int ch) {
    int yi = p / WI, xi = p % WI;
    float cy = yi * (19.0f / (HI - 1));
    float cx = xi * (19.0f / (WI - 1));
    int y0 = (int)cy; if (y0 > 19) y0 = 19;
    int x0 = (int)cx; if (x0 > 19) x0 = 19;
    int y1 = min(y0 + 1, 19);
    int x1 = min(x0 + 1, 19);
    float wy = cy - y0, wx = cx - x0;
    const float* base = psim + (size_t)b * HW2 * 4;
    float v00 = base[(y0 * 20 + x0) * 4 + ch];
    float v01 = base[(y0 * 20 + x1) * 4 + ch];
    float v10 = base[(y1 * 20 + x0) * 4 + ch];
    float v11 = base[(y1 * 20 + x1) * 4 + ch];
    float r0 = v00 * (1.f - wy) + v10 * wy;
    float r1 = v01 * (1.f - wy) + v11 * wy;
    return r0 * (1.f - wx) + r1 * wx;
}

// ---------------------------------------------------------------------------
// K_pack_sim (R17-validated): write 4 bf16 sim channels into xpackT.
// ---------------------------------------------------------------------------
template <int CI, int KP, int HW, int TILES, int HI, int WI>
static __device__ inline void pack_sim_body(int id, const float* __restrict__ psim,
                                            unsigned short* __restrict__ xp) {
    constexpr int KB = KP / 32;
    constexpr int KS = CI / 32;
    int b = id / HW, p = id % HW;
    int tile = p / 64, px = p % 64;
    unsigned int lo = (unsigned int)f2bf(bil<HI, WI>(psim, b, p, 0)) |
                      ((unsigned int)f2bf(bil<HI, WI>(psim, b, p, 1)) << 16);
    unsigned int hi = (unsigned int)f2bf(bil<HI, WI>(psim, b, p, 2)) |
                      ((unsigned int)f2bf(bil<HI, WI>(psim, b, p, 3)) << 16);
    uint2 u = {lo, hi};
    *(uint2*)(xp + ((size_t)(b * TILES + tile) * KB + KS) * 2048 + px * 32) = u;
}

__global__ __launch_bounds__(256) void k_pack_sim(
    const float* __restrict__ psim,
    unsigned short* __restrict__ xp0, unsigned short* __restrict__ xp1,
    unsigned short* __restrict__ xp2) {
    int id = blockIdx.x * 256 + threadIdx.x;
    if (id < 25600) {
        pack_sim_body<128, 160, 6400, 100, 80, 80>(id, psim, xp0);
        return;
    }
    id -= 25600;
    if (id < 6400) {
        pack_sim_body<256, 288, 1600, 25, 40, 40>(id, psim, xp1);
        return;
    }
    id -= 6400;
    if (id < 1600)
        pack_sim_body<512, 544, 400, 7, 20, 20>(id, psim, xp2);
}

// ---------------------------------------------------------------------------
// K_cost LDS fallback (R6-validated, mode0)
// ---------------------------------------------------------------------------
template <int NSP, int TS>
__global__ __launch_bounds__(128) void k_cost(const float* __restrict__ f2,
                                              float* __restrict__ Spart) {
    constexpr int CS = C2 / NSP;
    __shared__ float curT[2][28][36];
    int bi = blockIdx.x;
    int cs = bi % NSP;
    int rem = bi / NSP;
    int dy = rem % 9; rem /= 9;
    int t = rem % 3;
    int b = rem / 3;
    int tid = threadIdx.x;
    bool act = (tid < 100);
    int q = act ? tid : 0;
    int h = q / 5;
    int w0 = (q % 5) * 4;
    int p = h * W2 + w0;

    const float* cur = f2 + ((size_t)(b * TT + (TT - 1)) * C2 + cs * CS) * HW2;
    const float* pst = f2 + ((size_t)(b * TT + t) * C2 + cs * CS) * HW2;

    for (int i = tid; i < 2 * 28 * 36; i += 128)
        ((float*)curT)[i] = 0.f;
    __syncthreads();

    float acc[36];
#pragma unroll
    for (int i = 0; i < 36; ++i) acc[i] = 0.f;

    if (act) {
        float4 v = *(const float4*)(cur + p);
        *(float4*)&curT[0][h + 4][w0 + 4] = v;
    }
    __syncthreads();

    for (int c = 0; c < CS; ++c) {
        int buf = c & 1;
        if (act) {
            if (c + 1 < CS) {
                float4 v = *(const float4*)(cur + (size_t)(c + 1) * HW2 + p);
                *(float4*)&curT[buf ^ 1][h + 4][w0 + 4] = v;
            }
            const float* base = &curT[buf][h + dy][w0];
            float4 ql = *(const float4*)(base);
            float4 qm = *(const float4*)(base + 4);
            float4 qr = *(const float4*)(base + 8);
            float4 pv = *(const float4*)(pst + (size_t)c * HW2 + p);
            float cv[12] = {ql.x, ql.y, ql.z, ql.w,
                            qm.x, qm.y, qm.z, qm.w,
                            qr.x, qr.y, qr.z, qr.w};
#pragma unroll
            for (int dx = 0; dx < 9; ++dx) {
                acc[dx * 4 + 0] += fabsf(cv[dx + 0] - pv.x);
                acc[dx * 4 + 1] += fabsf(cv[dx + 1] - pv.y);
                acc[dx * 4 + 2] += fabsf(cv[dx + 2] - pv.z);
                acc[dx * 4 + 3] += fabsf(cv[dx + 3] - pv.w);
            }
        }
        __syncthreads();
    }

    if (act) {
        int tsbase = t * NS + dy * KK;
#pragma unroll
        for (int px = 0; px < 4; ++px) {
            float* dst = Spart + ((size_t)(cs * BB + b) * HW2 + (p + px)) * TS + tsbase;
#pragma unroll
            for (int dx = 0; dx < 9; ++dx) dst[dx] = -acc[dx * 4 + px];
        }
    }
}

// ---------------------------------------------------------------------------
// K_smax_conv1 (validated): NSP partials, TS stride, P12 index map
// ---------------------------------------------------------------------------
template <int NSP, int TS, bool P12>
__global__ __launch_bounds__(256) void k_smax_conv1(
    const float* __restrict__ Spart, const float* __restrict__ w1,
    const float* __restrict__ g1, const float* __restrict__ b1,
    const float* __restrict__ m1, const float* __restrict__ v1,
    float* __restrict__ psim) {
    __shared__ float sS[NTS];
    __shared__ float sP[NTS];
    int bp = blockIdx.x;
    int tid = threadIdx.x;
    if (tid < NTS) {
        int idx;
        if (P12) {
            int t = tid / 81, r = tid % 81;
            idx = t * 108 + (r / 9) * 12 + (r % 9);
        } else {
            idx = tid;
        }
        float S = 0.f;
#pragma unroll
        for (int k = 0; k < NSP; ++k)
            S += Spart[((size_t)(k * BB * HW2) + bp) * TS + idx];
        sS[tid] = S;
    }
    __syncthreads();
    int wave = tid >> 6, lane = tid & 63;
    if (wave < NT) {
        int base = wave * NS;
        float v0 = sS[base + lane];
        float vo = (lane < NS - 64) ? sS[base + 64 + lane] : -1e30f;
        float m = fmaxf(v0, vo);
#pragma unroll
        for (int off = 32; off; off >>= 1) m = fmaxf(m, __shfl_xor(m, off));
        float e0 = __expf(v0 - m);
        float e1 = (lane < NS - 64) ? __expf(vo - m) : 0.f;
        float s = e0 + e1;
#pragma unroll
        for (int off = 32; off; off >>= 1) s += __shfl_xor(s, off);
        float inv = 1.f / s;
        sP[base + lane] = e0 * inv;
        if (lane < NS - 64) sP[base + 64 + lane] = e1 * inv;
    }
    __syncthreads();
    if (tid < 64) {
        int o = tid >> 4, j = tid & 15;
        float acc = 0.f;
#pragma unroll
        for (int mm = 0; mm < 16; ++mm) {
            int k = j + (mm << 4);
            if (k < NTS) acc += w1[o * NTS + k] * sP[k];
        }
#pragma unroll
        for (int off = 8; off; off >>= 1) acc += __shfl_xor(acc, off);
        if (j == 0) {
            float sc = g1[o] * rsqrtf(v1[o] + EPSBN);
            float y = (acc - m1[o]) * sc + b1[o];
            float sig = 1.f / (1.f + __expf(-y));
            psim[(size_t)bp * HID + o] = y * sig;
        }
    }
}

// ---------------------------------------------------------------------------
// K_resize (fallback path only)
// ---------------------------------------------------------------------------
__global__ void k_resize(const float* __restrict__ psim, float* __restrict__ pre0,
                         float* __restrict__ pre1) {
    int id = blockIdx.x * 256 + threadIdx.x;
    int Hi, Wi, bb2, pp;
    float* dst;
    if (id < BB * 6400) {
        Hi = 80; Wi = 80; bb2 = id / 6400; pp = id % 6400; dst = pre0 + (size_t)id * 4;
    } else {
        id -= BB * 6400;
        if (id >= BB * 1600) return;
        Hi = 40; Wi = 40; bb2 = id / 1600; pp = id % 1600; dst = pre1 + (size_t)id * 4;
    }
    int yi = pp / Wi, xi = pp % Wi;
    float cy = yi * (19.0f / (Hi - 1));
    float cx = xi * (19.0f / (Wi - 1));
    int y0 = (int)cy; if (y0 > 19) y0 = 19;
    int x0 = (int)cx; if (x0 > 19) x0 = 19;
    int y1 = min(y0 + 1, 19);
    int x1 = min(x0 + 1, 19);
    float wy = cy - y0, wx = cx - x0;
    const float4* base = (const float4*)psim + (size_t)bb2 * HW2;
    float4 v00 = base[y0 * 20 + x0];
    float4 v01 = base[y0 * 20 + x1];
    float4 v10 = base[y1 * 20 + x0];
    float4 v11 = base[y1 * 20 + x1];
    float4 r0, r1, o4;
    r0.x = v00.x * (1.f - wy) + v10.x * wy; r0.y = v00.y * (1.f - wy) + v10.y * wy;
    r0.z = v00.z * (1.f - wy) + v10.z * wy; r0.w = v00.w * (1.f - wy) + v10.w * wy;
    r1.x = v01.x * (1.f - wy) + v11.x * wy; r1.y = v01.y * (1.f - wy) + v11.y * wy;
    r1.z = v01.z * (1.f - wy) + v11.z * wy; r1.w = v01.w * (1.f - wy) + v11.w * wy;
    o4.x = r0.x * (1.f - wx) + r1.x * wx; o4.y = r0.y * (1.f - wx) + r1.y * wx;
    o4.z = r0.z * (1.f - wx) + r1.z * wx; o4.w = r0.w * (1.f - wx) + r1.w * wx;
    *(float4*)dst = o4;
}

// ---------------------------------------------------------------------------
// gemmP body (R15/R16-validated): dbuf MFMA loop + LDS-transposed f4 epilogue
// ---------------------------------------------------------------------------
template <int O, int KP, int HW, int TILES>
static __device__ inline void gemmP_body(int lbid, const unsigned short* __restrict__ xp,
                                         const unsigned short* __restrict__ wbF,
                                         const float* __restrict__ shift,
                                         float* __restrict__ out,
                                         unsigned short* __restrict__ xls,
                                         float* __restrict__ cls_all) {
    constexpr int OB = O / 64;
    constexpr int KB = KP / 32;

    int tid = threadIdx.x;
    int lane = tid & 63, wv = tid >> 6;
    int ob = lbid % OB;
    int rest = lbid / OB;
    int b = rest / TILES;
    int tile = rest % TILES;
    int p0 = tile * 64;

    int l15 = lane & 15, lhi = lane >> 4;
    int o_w = ob * 64 + (wv & 1) * 32;
    int pw_loc = (wv >> 1) * 32;

    int o16 = o_w >> 4;
    const short8* a0p = (const short8*)wbF + ((size_t)o16 * KB) * 64 + lane;
    const short8* a1p = a0p + (size_t)KB * 64;
    const short8* chunk = (const short8*)(xp + ((size_t)(b * TILES + tile) * KB) * 2048);

    floatx4 acc00 = {0.f, 0.f, 0.f, 0.f}, acc01 = acc00, acc10 = acc00, acc11 = acc00;

    short8 v = chunk[tid];
    ((short8*)xls)[tid] = v;
    if (KB > 1) v = chunk[256 + tid];
    __syncthreads();

    for (int ks = 0; ks < KB; ++ks) {
        const unsigned short* buf = xls + (ks & 1) * 2048;
        short8 cb0 = *(const short8*)&buf[(pw_loc + l15) * 32 + lhi * 8];
        short8 cb1 = *(const short8*)&buf[(pw_loc + 16 + l15) * 32 + lhi * 8];
        if (ks + 1 < KB) {
            ((short8*)(xls + ((ks + 1) & 1) * 2048))[tid] = v;
            if (ks + 2 < KB) v = chunk[(ks + 2) * 256 + tid];
        }
        short8 ca0 = a0p[ks * 64];
        short8 ca1 = a1p[ks * 64];
        acc00 = __builtin_amdgcn_mfma_f32_16x16x32_bf16(ca0, cb0, acc00, 0, 0, 0);
        acc01 = __builtin_amdgcn_mfma_f32_16x16x32_bf16(ca0, cb1, acc01, 0, 0, 0);
        acc10 = __builtin_amdgcn_mfma_f32_16x16x32_bf16(ca1, cb0, acc10, 0, 0, 0);
        acc11 = __builtin_amdgcn_mfma_f32_16x16x32_bf16(ca1, cb1, acc11, 0, 0, 0);
        __syncthreads();
    }

    float* cls = cls_all + wv * (32 * 36);
#pragma unroll
    for (int osub = 0; osub < 2; ++osub) {
#pragma unroll
        for (int psub = 0; psub < 2; ++psub) {
            floatx4 d = osub ? (psub ? acc11 : acc10) : (psub ? acc01 : acc00);
#pragma unroll
            for (int r = 0; r < 4; ++r)
                cls[(osub * 16 + lhi * 4 + r) * 36 + psub * 16 + l15] = d[r];
        }
    }
#pragma unroll
    for (int i = 0; i < 4; ++i) {
        int o_loc = (lane >> 3) + i * 8;
        int pq = (lane & 7) * 4;
        int p = p0 + pw_loc + pq;
        if (p < HW) {
            float4 vv = *(float4*)&cls[o_loc * 36 + pq];
            int o = o_w + o_loc;
            float sh = shift[o];
            float4 so;
            float y;
            y = vv.x + sh; so.x = y / (1.f + __expf(-y));
            y = vv.y + sh; so.y = y / (1.f + __expf(-y));
            y = vv.z + sh; so.z = y / (1.f + __expf(-y));
            y = vv.w + sh; so.w = y / (1.f + __expf(-y));
            *(float4*)&out[((size_t)b * O + o) * HW + p] = so;
        }
    }
}

// merged gemm: L0 [0,800), L1 [800,1200), L2 [1200,1424)
__global__ __launch_bounds__(256) void k_gemmP_all(
    const unsigned short* __restrict__ xp0, const unsigned short* __restrict__ xp1,
    const unsigned short* __restrict__ xp2,
    const unsigned short* __restrict__ wb0, const unsigned short* __restrict__ wb1,
    const unsigned short* __restrict__ wb2,
    const float* __restrict__ shift, float* __restrict__ out) {
    __shared__ unsigned short xls[4096];
    __shared__ float cls[4 * 32 * 36];
    int bid = blockIdx.x;
    if (bid < 800) {
        gemmP_body<128, 160, 6400, 100>(bid, xp0, wb0, shift, out, xls, cls);
    } else if (bid < 1200) {
        gemmP_body<256, 288, 1600, 25>(bid - 800, xp1, wb1, shift + 128,
                                       out + 3276800, xls, cls);
    } else {
        gemmP_body<512, 544, 400, 7>(bid - 1200, xp2, wb2, shift + 384,
                                     out + 3276800 + 1638400, xls, cls);
    }
}

// ---------------------------------------------------------------------------
// K_gemm fused fallback (R3-validated, mode0 only; linear wb layout)
// ---------------------------------------------------------------------------
#define XLS_STRIDE 40
template <int O, int KP, int K, int HW, int TILES>
__global__ __launch_bounds__(256) void k_gemm(
    const float* __restrict__ f, const float* __restrict__ pre,
    const unsigned short* __restrict__ wb, const float* __restrict__ shift,
    float* __restrict__ out) {
    constexpr int CI = O;
    constexpr int OB = O / 64;
    __shared__ unsigned short xlsf[64 * XLS_STRIDE];

    int tid = threadIdx.x;
    int lane = tid & 63, wv = tid >> 6;
    int ob = blockIdx.x % OB;
    int rest = blockIdx.x / OB;
    int b = rest / TILES;
    int p0 = (rest % TILES) * 64;

    int l15 = lane & 15, lhi = lane >> 4;
    int o_w = ob * 64 + (wv & 1) * 32;
    int pw_loc = (wv >> 1) * 32;

    int c_l = tid >> 3;
    int pq = (tid & 7) * 8;
    const float* fbase = f + ((size_t)(b * TT + (TT - 1)) * CI) * HW;
    const float* pbase = pre + (size_t)b * HW * 4;

    const short8* aptr0 = (const short8*)(wb + (size_t)(o_w + l15) * KP + lhi * 8);
    const short8* aptr1 = (const short8*)(wb + (size_t)(o_w + 16 + l15) * KP + lhi * 8);

    floatx4 acc00 = {0.f, 0.f, 0.f, 0.f}, acc01 = acc00, acc10 = acc00, acc11 = acc00;

    for (int c0 = 0; c0 < KP; c0 += 32) {
        __syncthreads();
        {
            int c = c0 + c_l;
            float vals[8];
            if (c < CI) {
                const float* src = fbase + (size_t)c * HW + p0 + pq;
                if (p0 + pq + 7 < HW) {
                    float4 a = ((const float4*)src)[0];
                    float4 bq = ((const float4*)src)[1];
                    vals[0] = a.x; vals[1] = a.y; vals[2] = a.z; vals[3] = a.w;
                    vals[4] = bq.x; vals[5] = bq.y; vals[6] = bq.z; vals[7] = bq.w;
                } else {
#pragma unroll
                    for (int i = 0; i < 8; ++i) {
                        int p = p0 + pq + i;
                        vals[i] = (p < HW) ? src[i] : 0.f;
                    }
                }
            } else if (c < K) {
#pragma unroll
                for (int i = 0; i < 8; ++i) {
                    int p = p0 + pq + i;
                    vals[i] = (p < HW) ? pbase[(size_t)p * 4 + (c - CI)] : 0.f;
                }
            } else {
#pragma unroll
                for (int i = 0; i < 8; ++i) vals[i] = 0.f;
            }
#pragma unroll
            for (int i = 0; i < 8; ++i)
                xlsf[(pq + i) * XLS_STRIDE + c_l] = f2bf(vals[i]);
        }
        __syncthreads();

        short8 ca0 = aptr0[c0 >> 3];
        short8 ca1 = aptr1[c0 >> 3];
        short8 cb0 = *(const short8*)&xlsf[(pw_loc + l15) * XLS_STRIDE + lhi * 8];
        short8 cb1 = *(const short8*)&xlsf[(pw_loc + 16 + l15) * XLS_STRIDE + lhi * 8];
        acc00 = __builtin_amdgcn_mfma_f32_16x16x32_bf16(ca0, cb0, acc00, 0, 0, 0);
        acc01 = __builtin_amdgcn_mfma_f32_16x16x32_bf16(ca0, cb1, acc01, 0, 0, 0);
        acc10 = __builtin_amdgcn_mfma_f32_16x16x32_bf16(ca1, cb0, acc10, 0, 0, 0);
        acc11 = __builtin_amdgcn_mfma_f32_16x16x32_bf16(ca1, cb1, acc11, 0, 0, 0);
    }

#pragma unroll
    for (int osub = 0; osub < 2; ++osub) {
#pragma unroll
        for (int psub = 0; psub < 2; ++psub) {
            floatx4 d = osub ? (psub ? acc11 : acc10) : (psub ? acc01 : acc00);
            int p = p0 + pw_loc + psub * 16 + l15;
            int obase = o_w + osub * 16 + lhi * 4;
            if (p < HW) {
#pragma unroll
                for (int r = 0; r < 4; ++r) {
                    int o = obase + r;
                    float y = d[r] + shift[o];
                    float sig = 1.f / (1.f + __expf(-y));
                    out[((size_t)b * O + o) * HW + p] = y * sig;
                }
            }
        }
    }
}

// ---------------------------------------------------------------------------
extern "C" void kernel_launch(void* const* d_in, const int* in_sizes, int n_in,
                              void* d_out, int out_size, void* d_ws, size_t ws_size,
                              hipStream_t stream) {
    const float* f0 = (const float*)d_in[0];
    const float* f1 = (const float*)d_in[1];
    const float* f2 = (const float*)d_in[2];
    const float* w1 = (const float*)d_in[5];
    const float* g1 = (const float*)d_in[6];
    const float* b1 = (const float*)d_in[7];
    const float* m1 = (const float*)d_in[8];
    const float* v1 = (const float*)d_in[9];
    const float* w2_0 = (const float*)d_in[10];
    const float* g2_0 = (const float*)d_in[11];
    const float* b2_0 = (const float*)d_in[12];
    const float* m2_0 = (const float*)d_in[13];
    const float* v2_0 = (const float*)d_in[14];
    const float* w2_1 = (const float*)d_in[15];
    const float* g2_1 = (const float*)d_in[16];
    const float* b2_1 = (const float*)d_in[17];
    const float* m2_1 = (const float*)d_in[18];
    const float* v2_1 = (const float*)d_in[19];
    const float* w2_2 = (const float*)d_in[20];
    const float* g2_2 = (const float*)d_in[21];
    const float* b2_2 = (const float*)d_in[22];
    const float* m2_2 = (const float*)d_in[23];
    const float* v2_2 = (const float*)d_in[24];

    float* ws = (float*)d_ws;
    const size_t PADSZ = (size_t)BB * C2 * 28 * 32;          // 1,835,008 fl
    const size_t SP336_8 = (size_t)8 * BB * HW2 * 336;       // 4,300,800 fl
    const size_t SP8 = (size_t)8 * BB * HW2 * 256;           // 3,276,800 fl
    const size_t XP0 = 2048000, XP1 = 921600, XP2 = 487424;  // floats
    const size_t need2 =
        (SP336_8 + PADSZ + 6400 + 10240 + 36864 + 139264 + 896 + XP0 + XP1 + XP2) * 4;
    int mode = (ws_size >= need2) ? 2 : 0;

    float* out = (float*)d_out;

    if (mode == 2) {
        float* Spart = ws;
        float* pad = ws + SP336_8;
        float* psim = pad + PADSZ;
        unsigned short* wb0 = (unsigned short*)(psim + 6400);
        unsigned short* wb1 = wb0 + 20480;
        unsigned short* wb2 = wb1 + 73728;
        float* shift = (float*)(wb2 + 278528);
        float* xb = shift + 896;
        unsigned short* xp0 = (unsigned short*)xb;
        unsigned short* xp1 = (unsigned short*)(xb + XP0);
        unsigned short* xp2 = (unsigned short*)(xb + XP0 + XP1);

        k_prep_pad<<<dim3(3252), dim3(256), 0, stream>>>(
            f2, pad,
            w2_0, w2_1, w2_2,
            g2_0, b2_0, m2_0, v2_0,
            g2_1, b2_1, m2_1, v2_1,
            g2_2, b2_2, m2_2, v2_2,
            wb0, wb1, wb2, shift);
        k_cost_packf<<<dim3(4240), dim3(256), 0, stream>>>(
            f2, pad, Spart, f0, f1, xp0, xp1, xp2);
        k_smax_conv1<8, 336, true><<<dim3(1600), dim3(256), 0, stream>>>(
            Spart, w1, g1, b1, m1, v1, psim);
        k_pack_sim<<<dim3(132), dim3(256), 0, stream>>>(psim, xp0, xp1, xp2);
        k_gemmP_all<<<dim3(1424), dim3(256), 0, stream>>>(
            xp0, xp1, xp2, wb0, wb1, wb2, shift, out);
    } else {
        float* Spart = ws;
        float* psim = ws + SP8;
        float* pre0 = psim + 6400;
        float* pre1 = pre0 + 102400;
        unsigned short* wb0 = (unsigned short*)(pre1 + 25600);
        unsigned short* wb1 = wb0 + 20480;
        unsigned short* wb2 = wb1 + 73728;
        float* shift = (float*)(wb2 + 278528);

        k_prep<<<dim3(1460), dim3(256), 0, stream>>>(
            w2_0, w2_1, w2_2,
            g2_0, b2_0, m2_0, v2_0,
            g2_1, b2_1, m2_1, v2_1,
            g2_2, b2_2, m2_2, v2_2,
            wb0, wb1, wb2, shift);
        k_cost<8, 256><<<dim3(8 * 108), dim3(128), 0, stream>>>(f2, Spart);
        k_smax_conv1<8, 256, false><<<dim3(1600), dim3(256), 0, stream>>>(
            Spart, w1, g1, b1, m1, v1, psim);
        k_resize<<<dim3(125), dim3(256), 0, stream>>>(psim, pre0, pre1);
        k_gemm<128, 160, 132, 6400, 100><<<dim3(800), dim3(256), 0, stream>>>(
            f0, pre0, wb0, shift, out);
        k_gemm<256, 288, 260, 1600, 25><<<dim3(400), dim3(256), 0, stream>>>(
            f1, pre1, wb1, shift + 128, out + 3276800);
        k_gemm<512, 544, 516, 400, 7><<<dim3(224), dim3(256), 0, stream>>>(
            f2, psim, wb2, shift + 384, out + 3276800 + 1638400);
    }
}

// Round 20
// 60.628 us; speedup vs baseline: 1.1727x; 1.0296x over previous
//
#include <hip/hip_runtime.h>
#include <math.h>

#define EPSBN 1e-3f

// geometry
#define BB 4
#define TT 4
#define C2 512
#define H2 20
#define W2 20
#define HW2 400
#define RR 4
#define KK 9
#define NS 81
#define NT 3
#define NTS 243
#define HID 4

typedef __attribute__((ext_vector_type(8))) short short8;
typedef __attribute__((ext_vector_type(4))) float floatx4;

static __device__ inline unsigned short f2bf(float f) {
    unsigned int u = __float_as_uint(f);
    unsigned int r = (u + 0x7fffu + ((u >> 16) & 1u)) >> 16;
    return (unsigned short)r;
}

// ---------------------------------------------------------------------------
// prep_frag: conv2 weights -> bf16 MFMA-fragment layout (R12/R13-validated)
// ---------------------------------------------------------------------------
static __device__ inline void prep_frag_body(
    int i,
    const float* __restrict__ w0, const float* __restrict__ w1,
    const float* __restrict__ w2,
    const float* __restrict__ g0, const float* __restrict__ b0,
    const float* __restrict__ m0, const float* __restrict__ v0,
    const float* __restrict__ g1, const float* __restrict__ b1,
    const float* __restrict__ m1, const float* __restrict__ v1,
    const float* __restrict__ g2, const float* __restrict__ b2,
    const float* __restrict__ m2, const float* __restrict__ v2,
    unsigned short* __restrict__ wb0, unsigned short* __restrict__ wb1,
    unsigned short* __restrict__ wb2, float* __restrict__ shift) {
    if (i < 20480) {  // L0: KB=5
        int j = i & 7, lane = (i >> 3) & 63;
        int blk = i >> 9;
        int kb = blk % 5, o16 = blk / 5;
        int o = o16 * 16 + (lane & 15);
        int k = kb * 32 + (lane >> 4) * 8 + j;
        float sc = g0[o] * rsqrtf(v0[o] + EPSBN);
        wb0[i] = f2bf(k < 132 ? w0[o * 132 + k] * sc : 0.f);
        return;
    }
    i -= 20480;
    if (i < 73728) {  // L1: KB=9
        int j = i & 7, lane = (i >> 3) & 63;
        int blk = i >> 9;
        int kb = blk % 9, o16 = blk / 9;
        int o = o16 * 16 + (lane & 15);
        int k = kb * 32 + (lane >> 4) * 8 + j;
        float sc = g1[o] * rsqrtf(v1[o] + EPSBN);
        wb1[i] = f2bf(k < 260 ? w1[o * 260 + k] * sc : 0.f);
        return;
    }
    i -= 73728;
    if (i < 278528) {  // L2: KB=17
        int j = i & 7, lane = (i >> 3) & 63;
        int blk = i >> 9;
        int kb = blk % 17, o16 = blk / 17;
        int o = o16 * 16 + (lane & 15);
        int k = kb * 32 + (lane >> 4) * 8 + j;
        float sc = g2[o] * rsqrtf(v2[o] + EPSBN);
        wb2[i] = f2bf(k < 516 ? w2[o * 516 + k] * sc : 0.f);
        return;
    }
    i -= 278528;
    if (i < 896) {
        if (i < 128) {
            float sc = g0[i] * rsqrtf(v0[i] + EPSBN);
            shift[i] = b0[i] - m0[i] * sc;
        } else if (i < 384) {
            int o = i - 128;
            float sc = g1[o] * rsqrtf(v1[o] + EPSBN);
            shift[i] = b1[o] - m1[o] * sc;
        } else {
            int o = i - 384;
            float sc = g2[o] * rsqrtf(v2[o] + EPSBN);
            shift[i] = b2[o] - m2[o] * sc;
        }
    }
}

// linear prep (fallback path, R1-validated)
static __device__ inline void prep_body(
    int i,
    const float* __restrict__ w0, const float* __restrict__ w1,
    const float* __restrict__ w2,
    const float* __restrict__ g0, const float* __restrict__ b0,
    const float* __restrict__ m0, const float* __restrict__ v0,
    const float* __restrict__ g1, const float* __restrict__ b1,
    const float* __restrict__ m1, const float* __restrict__ v1,
    const float* __restrict__ g2, const float* __restrict__ b2,
    const float* __restrict__ m2, const float* __restrict__ v2,
    unsigned short* __restrict__ wb0, unsigned short* __restrict__ wb1,
    unsigned short* __restrict__ wb2, float* __restrict__ shift) {
    if (i < 128 * 160) {
        int o = i / 160, k = i % 160;
        float sc = g0[o] * rsqrtf(v0[o] + EPSBN);
        wb0[i] = f2bf(k < 132 ? w0[o * 132 + k] * sc : 0.f);
        return;
    }
    i -= 128 * 160;
    if (i < 256 * 288) {
        int o = i / 288, k = i % 288;
        float sc = g1[o] * rsqrtf(v1[o] + EPSBN);
        wb1[i] = f2bf(k < 260 ? w1[o * 260 + k] * sc : 0.f);
        return;
    }
    i -= 256 * 288;
    if (i < 512 * 544) {
        int o = i / 544, k = i % 544;
        float sc = g2[o] * rsqrtf(v2[o] + EPSBN);
        wb2[i] = f2bf(k < 516 ? w2[o * 516 + k] * sc : 0.f);
        return;
    }
    i -= 512 * 544;
    if (i < 896) {
        if (i < 128) {
            float sc = g0[i] * rsqrtf(v0[i] + EPSBN);
            shift[i] = b0[i] - m0[i] * sc;
        } else if (i < 384) {
            int o = i - 128;
            float sc = g1[o] * rsqrtf(v1[o] + EPSBN);
            shift[i] = b1[o] - m1[o] * sc;
        } else {
            int o = i - 384;
            float sc = g2[o] * rsqrtf(v2[o] + EPSBN);
            shift[i] = b2[o] - m2[o] * sc;
        }
    }
}

__global__ void k_prep(const float* w0, const float* w1, const float* w2,
                       const float* g0, const float* b0, const float* m0, const float* v0,
                       const float* g1, const float* b1, const float* m1, const float* v1,
                       const float* g2, const float* b2, const float* m2, const float* v2,
                       unsigned short* wb0, unsigned short* wb1,
                       unsigned short* wb2, float* shift) {
    int i = blockIdx.x * 256 + threadIdx.x;
    prep_body(i, w0, w1, w2, g0, b0, m0, v0, g1, b1, m1, v1, g2, b2, m2, v2,
              wb0, wb1, wb2, shift);
}

// ---------------------------------------------------------------------------
// K_prep_pad: fused fragment-prep + zero-padded last-frame copy (R13-validated)
// ---------------------------------------------------------------------------
__global__ void k_prep_pad(const float* __restrict__ f2, float* __restrict__ pad,
                           const float* w0, const float* w1, const float* w2,
                           const float* g0, const float* b0, const float* m0, const float* v0,
                           const float* g1, const float* b1, const float* m1, const float* v1,
                           const float* g2, const float* b2, const float* m2, const float* v2,
                           unsigned short* wb0, unsigned short* wb1,
                           unsigned short* wb2, float* shift) {
    int bid = blockIdx.x;
    if (bid < 1792) {
        int id = bid * 256 + threadIdx.x;           // float4 index
        if (id >= BB * C2 * 28 * 8) return;
        int c4 = id & 7;
        int tmp = id >> 3;
        int r = tmp % 28;
        int tmp2 = tmp / 28;
        int c = tmp2 % C2;
        int b = tmp2 / C2;
        float4 v = {0.f, 0.f, 0.f, 0.f};
        if (r >= 4 && r < 24 && c4 >= 1 && c4 <= 5)
            v = *(const float4*)(f2 + ((size_t)(b * TT + (TT - 1)) * C2 + c) * HW2 +
                                 (r - 4) * W2 + (c4 - 1) * 4);
        *(float4*)(pad + (size_t)id * 4) = v;
    } else {
        int i = (bid - 1792) * 256 + threadIdx.x;
        prep_frag_body(i, w0, w1, w2, g0, b0, m0, v0, g1, b1, m1, v1, g2, b2, m2, v2,
                       wb0, wb1, wb2, shift);
    }
}

// ---------------------------------------------------------------------------
// cost_cs body (R16/R17-validated: register path, pipelined loads, f4 stores)
// ---------------------------------------------------------------------------
template <int NSPG>
static __device__ inline void cost_cs_body(int bi, const float* __restrict__ f2,
                                           const float* __restrict__ pad,
                                           float* __restrict__ Spart) {
    constexpr int CS = C2 / (NSPG * 2);
    __shared__ float red[36][100];
    int cs = bi % NSPG;
    int rem = bi / NSPG;
    int dy = rem % 9; rem /= 9;
    int t = rem % 3;
    int b = rem / 3;
    int tid = threadIdx.x;
    int half = tid >> 7;
    int q = tid & 127;
    bool act = (q < 100);
    int qq = act ? q : 0;
    int h = qq / 5;
    int w0 = (qq % 5) * 4;
    int p = h * W2 + w0;
    int c0 = cs * (2 * CS) + half * CS;

    const float* pr = pad + ((size_t)(b * C2 + c0) * 28 + (h + dy)) * 32 + w0;
    const float* pp = f2 + ((size_t)(b * TT + t) * C2 + c0) * HW2 + p;

    float acc[36];
#pragma unroll
    for (int i = 0; i < 36; ++i) acc[i] = 0.f;

    if (act) {
        float4 ql = *(const float4*)(pr);
        float4 qm = *(const float4*)(pr + 4);
        float4 qr = *(const float4*)(pr + 8);
        float4 pv = *(const float4*)(pp);
        for (int c = 0; c < CS; ++c) {
            float4 nql, nqm, nqr, npv;
            if (c + 1 < CS) {
                pr += 28 * 32;
                pp += HW2;
                nql = *(const float4*)(pr);
                nqm = *(const float4*)(pr + 4);
                nqr = *(const float4*)(pr + 8);
                npv = *(const float4*)(pp);
            }
            float cv[12] = {ql.x, ql.y, ql.z, ql.w,
                            qm.x, qm.y, qm.z, qm.w,
                            qr.x, qr.y, qr.z, qr.w};
#pragma unroll
            for (int dx = 0; dx < 9; ++dx) {
                acc[dx * 4 + 0] += fabsf(cv[dx + 0] - pv.x);
                acc[dx * 4 + 1] += fabsf(cv[dx + 1] - pv.y);
                acc[dx * 4 + 2] += fabsf(cv[dx + 2] - pv.z);
                acc[dx * 4 + 3] += fabsf(cv[dx + 3] - pv.w);
            }
            ql = nql; qm = nqm; qr = nqr; pv = npv;
        }
    }

    if (half == 1 && act) {
#pragma unroll
        for (int i = 0; i < 36; ++i) red[i][qq] = acc[i];
    }
    __syncthreads();
    if (half == 0 && act) {
#pragma unroll
        for (int i = 0; i < 36; ++i) acc[i] += red[i][qq];
#pragma unroll
        for (int px = 0; px < 4; ++px) {
            float* dst = Spart + ((size_t)(cs * BB + b) * HW2 + (p + px)) * 336 +
                         t * 108 + dy * 12;
            float4 u0 = {-acc[0 + px], -acc[4 + px], -acc[8 + px], -acc[12 + px]};
            float4 u1 = {-acc[16 + px], -acc[20 + px], -acc[24 + px], -acc[28 + px]};
            float4 u2 = {-acc[32 + px], 0.f, 0.f, 0.f};
            *(float4*)(dst) = u0;
            *(float4*)(dst + 4) = u1;
            *(float4*)(dst + 8) = u2;
        }
    }
}

// ---------------------------------------------------------------------------
// pack_f body (R16/R17-validated): f-channel part of xpackT, sim slots zeroed.
// ---------------------------------------------------------------------------
template <int CI, int KP, int HW, int TILES>
static __device__ inline void pack_f_body(int cid, const float* __restrict__ f,
                                          unsigned short* __restrict__ xp) {
    constexpr int KB = KP / 32;
    int tid = threadIdx.x;
    int b = cid / (TILES * KB);
    int rem = cid % (TILES * KB);
    int tile = rem / KB;
    int ks = rem % KB;
    int px = tid >> 2;
    int p = tile * 64 + px;
    int c0 = ks * 32 + (tid & 3) * 8;
    bool pok = (p < HW);
    const float* fb = f + ((size_t)(b * TT + (TT - 1)) * CI) * HW + p;

    short8 o;
#pragma unroll
    for (int j = 0; j < 8; ++j) {
        int c = c0 + j;
        float v = 0.f;
        if (pok && c < CI) v = fb[(size_t)c * HW];
        o[j] = (short)f2bf(v);
    }
    ((short8*)(xp + ((size_t)(b * TILES + tile) * KB + ks) * 2048))[tid] = o;
}

// ---------------------------------------------------------------------------
// K_cost_packf: co-dispatch cost (latency-bound, low occupancy) with the
// independent pack_f work to fill idle SIMDs. blocks [0,864): cost;
// [864,2864): L0 pack; [2864,3764): L1; [3764,4240): L2.
// ---------------------------------------------------------------------------
__global__ __launch_bounds__(256) void k_cost_packf(
    const float* __restrict__ f2, const float* __restrict__ pad,
    float* __restrict__ Spart,
    const float* __restrict__ f0, const float* __restrict__ f1,
    unsigned short* __restrict__ xp0, unsigned short* __restrict__ xp1,
    unsigned short* __restrict__ xp2) {
    int bid = blockIdx.x;
    if (bid < 864) {
        cost_cs_body<8>(bid, f2, pad, Spart);
    } else {
        int pb = bid - 864;
        if (pb < 2000) {
            pack_f_body<128, 160, 6400, 100>(pb, f0, xp0);
        } else if (pb < 2900) {
            pack_f_body<256, 288, 1600, 25>(pb - 2000, f1, xp1);
        } else {
            pack_f_body<512, 544, 400, 7>(pb - 2900, f2, xp2);
        }
    }
}

// ---------------------------------------------------------------------------
// bilinear sample of psim[b][400][4]; for HI=WI=20 degenerates to identity.
// ---------------------------------------------------------------------------
template <int HI, int WI>
static __device__ inline float bil(const float* __restrict__ psim, int b, int p, int ch) {
    int yi = p / WI, xi = p % WI;
    float cy = yi * (19.0f / (HI - 1));
    float cx = xi * (19.0f / (WI - 1));
    int y0 = (int)cy; if (y0 > 19) y0 = 19;
    int x0 = (int)cx; if (x0 > 19) x0 = 19;
    int y1 = min(y0 + 1, 19);
    int x1 = min(x0 + 1, 19);
    float wy = cy - y0, wx = cx - x0;
    const float* base = psim + (size_t)b * HW2 * 4;
    float v00 = base[(y0 * 20 + x0) * 4 + ch];
    float v01 = base[(y0 * 20 + x1) * 4 + ch];
    float v10 = base[(y1 * 20 + x0) * 4 + ch];
    float v11 = base[(y1 * 20 + x1) * 4 + ch];
    float r0 = v00 * (1.f - wy) + v10 * wy;
    float r1 = v01 * (1.f - wy) + v11 * wy;
    return r0 * (1.f - wx) + r1 * wx;
}

// ---------------------------------------------------------------------------
// K_pack_sim (R17-validated): write 4 bf16 sim channels into xpackT.
// ---------------------------------------------------------------------------
template <int CI, int KP, int HW, int TILES, int HI, int WI>
static __device__ inline void pack_sim_body(int id, const float* __restrict__ psim,
                                            unsigned short* __restrict__ xp) {
    constexpr int KB = KP / 32;
    constexpr int KS = CI / 32;
    int b = id / HW, p = id % HW;
    int tile = p / 64, px = p % 64;
    unsigned int lo = (unsigned int)f2bf(bil<HI, WI>(psim, b, p, 0)) |
                      ((unsigned int)f2bf(bil<HI, WI>(psim, b, p, 1)) << 16);
    unsigned int hi = (unsigned int)f2bf(bil<HI, WI>(psim, b, p, 2)) |
                      ((unsigned int)f2bf(bil<HI, WI>(psim, b, p, 3)) << 16);
    uint2 u = {lo, hi};
    *(uint2*)(xp + ((size_t)(b * TILES + tile) * KB + KS) * 2048 + px * 32) = u;
}

__global__ __launch_bounds__(256) void k_pack_sim(
    const float* __restrict__ psim,
    unsigned short* __restrict__ xp0, unsigned short* __restrict__ xp1,
    unsigned short* __restrict__ xp2) {
    int id = blockIdx.x * 256 + threadIdx.x;
    if (id < 25600) {
        pack_sim_body<128, 160, 6400, 100, 80, 80>(id, psim, xp0);
        return;
    }
    id -= 25600;
    if (id < 6400) {
        pack_sim_body<256, 288, 1600, 25, 40, 40>(id, psim, xp1);
        return;
    }
    id -= 6400;
    if (id < 1600)
        pack_sim_body<512, 544, 400, 7, 20, 20>(id, psim, xp2);
}

// ---------------------------------------------------------------------------
// K_cost LDS fallback (R6-validated, mode0)
// ---------------------------------------------------------------------------
template <int NSP, int TS>
__global__ __launch_bounds__(128) void k_cost(const float* __restrict__ f2,
                                              float* __restrict__ Spart) {
    constexpr int CS = C2 / NSP;
    __shared__ float curT[2][28][36];
    int bi = blockIdx.x;
    int cs = bi % NSP;
    int rem = bi / NSP;
    int dy = rem % 9; rem /= 9;
    int t = rem % 3;
    int b = rem / 3;
    int tid = threadIdx.x;
    bool act = (tid < 100);
    int q = act ? tid : 0;
    int h = q / 5;
    int w0 = (q % 5) * 4;
    int p = h * W2 + w0;

    const float* cur = f2 + ((size_t)(b * TT + (TT - 1)) * C2 + cs * CS) * HW2;
    const float* pst = f2 + ((size_t)(b * TT + t) * C2 + cs * CS) * HW2;

    for (int i = tid; i < 2 * 28 * 36; i += 128)
        ((float*)curT)[i] = 0.f;
    __syncthreads();

    float acc[36];
#pragma unroll
    for (int i = 0; i < 36; ++i) acc[i] = 0.f;

    if (act) {
        float4 v = *(const float4*)(cur + p);
        *(float4*)&curT[0][h + 4][w0 + 4] = v;
    }
    __syncthreads();

    for (int c = 0; c < CS; ++c) {
        int buf = c & 1;
        if (act) {
            if (c + 1 < CS) {
                float4 v = *(const float4*)(cur + (size_t)(c + 1) * HW2 + p);
                *(float4*)&curT[buf ^ 1][h + 4][w0 + 4] = v;
            }
            const float* base = &curT[buf][h + dy][w0];
            float4 ql = *(const float4*)(base);
            float4 qm = *(const float4*)(base + 4);
            float4 qr = *(const float4*)(base + 8);
            float4 pv = *(const float4*)(pst + (size_t)c * HW2 + p);
            float cv[12] = {ql.x, ql.y, ql.z, ql.w,
                            qm.x, qm.y, qm.z, qm.w,
                            qr.x, qr.y, qr.z, qr.w};
#pragma unroll
            for (int dx = 0; dx < 9; ++dx) {
                acc[dx * 4 + 0] += fabsf(cv[dx + 0] - pv.x);
                acc[dx * 4 + 1] += fabsf(cv[dx + 1] - pv.y);
                acc[dx * 4 + 2] += fabsf(cv[dx + 2] - pv.z);
                acc[dx * 4 + 3] += fabsf(cv[dx + 3] - pv.w);
            }
        }
        __syncthreads();
    }

    if (act) {
        int tsbase = t * NS + dy * KK;
#pragma unroll
        for (int px = 0; px < 4; ++px) {
            float* dst = Spart + ((size_t)(cs * BB + b) * HW2 + (p + px)) * TS + tsbase;
#pragma unroll
            for (int dx = 0; dx < 9; ++dx) dst[dx] = -acc[dx * 4 + px];
        }
    }
}

// ---------------------------------------------------------------------------
// K_smax_conv1 (validated): NSP partials, TS stride, P12 index map
// ---------------------------------------------------------------------------
template <int NSP, int TS, bool P12>
__global__ __launch_bounds__(256) void k_smax_conv1(
    const float* __restrict__ Spart, const float* __restrict__ w1,
    const float* __restrict__ g1, const float* __restrict__ b1,
    const float* __restrict__ m1, const float* __restrict__ v1,
    float* __restrict__ psim) {
    __shared__ float sS[NTS];
    __shared__ float sP[NTS];
    int bp = blockIdx.x;
    int tid = threadIdx.x;
    if (tid < NTS) {
        int idx;
        if (P12) {
            int t = tid / 81, r = tid % 81;
            idx = t * 108 + (r / 9) * 12 + (r % 9);
        } else {
            idx = tid;
        }
        float S = 0.f;
#pragma unroll
        for (int k = 0; k < NSP; ++k)
            S += Spart[((size_t)(k * BB * HW2) + bp) * TS + idx];
        sS[tid] = S;
    }
    __syncthreads();
    int wave = tid >> 6, lane = tid & 63;
    if (wave < NT) {
        int base = wave * NS;
        float v0 = sS[base + lane];
        float vo = (lane < NS - 64) ? sS[base + 64 + lane] : -1e30f;
        float m = fmaxf(v0, vo);
#pragma unroll
        for (int off = 32; off; off >>= 1) m = fmaxf(m, __shfl_xor(m, off));
        float e0 = __expf(v0 - m);
        float e1 = (lane < NS - 64) ? __expf(vo - m) : 0.f;
        float s = e0 + e1;
#pragma unroll
        for (int off = 32; off; off >>= 1) s += __shfl_xor(s, off);
        float inv = 1.f / s;
        sP[base + lane] = e0 * inv;
        if (lane < NS - 64) sP[base + 64 + lane] = e1 * inv;
    }
    __syncthreads();
    if (tid < 64) {
        int o = tid >> 4, j = tid & 15;
        float acc = 0.f;
#pragma unroll
        for (int mm = 0; mm < 16; ++mm) {
            int k = j + (mm << 4);
            if (k < NTS) acc += w1[o * NTS + k] * sP[k];
        }
#pragma unroll
        for (int off = 8; off; off >>= 1) acc += __shfl_xor(acc, off);
        if (j == 0) {
            float sc = g1[o] * rsqrtf(v1[o] + EPSBN);
            float y = (acc - m1[o]) * sc + b1[o];
            float sig = 1.f / (1.f + __expf(-y));
            psim[(size_t)bp * HID + o] = y * sig;
        }
    }
}

// ---------------------------------------------------------------------------
// K_resize (fallback path only)
// ---------------------------------------------------------------------------
__global__ void k_resize(const float* __restrict__ psim, float* __restrict__ pre0,
                         float* __restrict__ pre1) {
    int id = blockIdx.x * 256 + threadIdx.x;
    int Hi, Wi, bb2, pp;
    float* dst;
    if (id < BB * 6400) {
        Hi = 80; Wi = 80; bb2 = id / 6400; pp = id % 6400; dst = pre0 + (size_t)id * 4;
    } else {
        id -= BB * 6400;
        if (id >= BB * 1600) return;
        Hi = 40; Wi = 40; bb2 = id / 1600; pp = id % 1600; dst = pre1 + (size_t)id * 4;
    }
    int yi = pp / Wi, xi = pp % Wi;
    float cy = yi * (19.0f / (Hi - 1));
    float cx = xi * (19.0f / (Wi - 1));
    int y0 = (int)cy; if (y0 > 19) y0 = 19;
    int x0 = (int)cx; if (x0 > 19) x0 = 19;
    int y1 = min(y0 + 1, 19);
    int x1 = min(x0 + 1, 19);
    float wy = cy - y0, wx = cx - x0;
    const float4* base = (const float4*)psim + (size_t)bb2 * HW2;
    float4 v00 = base[y0 * 20 + x0];
    float4 v01 = base[y0 * 20 + x1];
    float4 v10 = base[y1 * 20 + x0];
    float4 v11 = base[y1 * 20 + x1];
    float4 r0, r1, o4;
    r0.x = v00.x * (1.f - wy) + v10.x * wy; r0.y = v00.y * (1.f - wy) + v10.y * wy;
    r0.z = v00.z * (1.f - wy) + v10.z * wy; r0.w = v00.w * (1.f - wy) + v10.w * wy;
    r1.x = v01.x * (1.f - wy) + v11.x * wy; r1.y = v01.y * (1.f - wy) + v11.y * wy;
    r1.z = v01.z * (1.f - wy) + v11.z * wy; r1.w = v01.w * (1.f - wy) + v11.w * wy;
    o4.x = r0.x * (1.f - wx) + r1.x * wx; o4.y = r0.y * (1.f - wx) + r1.y * wx;
    o4.z = r0.z * (1.f - wx) + r1.z * wx; o4.w = r0.w * (1.f - wx) + r1.w * wx;
    *(float4*)dst = o4;
}

// ---------------------------------------------------------------------------
// gemmP body (R15/R16-validated): dbuf MFMA loop + LDS-transposed f4 epilogue
// ---------------------------------------------------------------------------
template <int O, int KP, int HW, int TILES>
static __device__ inline void gemmP_body(int lbid, const unsigned short* __restrict__ xp,
                                         const unsigned short* __restrict__ wbF,
                                         const float* __restrict__ shift,
                                         float* __restrict__ out,
                                         unsigned short* __restrict__ xls,
                                         float* __restrict__ cls_all) {
    constexpr int OB = O / 64;
    constexpr int KB = KP / 32;

    int tid = threadIdx.x;
    int lane = tid & 63, wv = tid >> 6;
    int ob = lbid % OB;
    int rest = lbid / OB;
    int b = rest / TILES;
    int tile = rest % TILES;
    int p0 = tile * 64;

    int l15 = lane & 15, lhi = lane >> 4;
    int o_w = ob * 64 + (wv & 1) * 32;
    int pw_loc = (wv >> 1) * 32;

    int o16 = o_w >> 4;
    const short8* a0p = (const short8*)wbF + ((size_t)o16 * KB) * 64 + lane;
    const short8* a1p = a0p + (size_t)KB * 64;
    const short8* chunk = (const short8*)(xp + ((size_t)(b * TILES + tile) * KB) * 2048);

    floatx4 acc00 = {0.f, 0.f, 0.f, 0.f}, acc01 = acc00, acc10 = acc00, acc11 = acc00;

    short8 v = chunk[tid];
    ((short8*)xls)[tid] = v;
    if (KB > 1) v = chunk[256 + tid];
    __syncthreads();

    for (int ks = 0; ks < KB; ++ks) {
        const unsigned short* buf = xls + (ks & 1) * 2048;
        short8 cb0 = *(const short8*)&buf[(pw_loc + l15) * 32 + lhi * 8];
        short8 cb1 = *(const short8*)&buf[(pw_loc + 16 + l15) * 32 + lhi * 8];
        if (ks + 1 < KB) {
            ((short8*)(xls + ((ks + 1) & 1) * 2048))[tid] = v;
            if (ks + 2 < KB) v = chunk[(ks + 2) * 256 + tid];
        }
        short8 ca0 = a0p[ks * 64];
        short8 ca1 = a1p[ks * 64];
        acc00 = __builtin_amdgcn_mfma_f32_16x16x32_bf16(ca0, cb0, acc00, 0, 0, 0);
        acc01 = __builtin_amdgcn_mfma_f32_16x16x32_bf16(ca0, cb1, acc01, 0, 0, 0);
        acc10 = __builtin_amdgcn_mfma_f32_16x16x32_bf16(ca1, cb0, acc10, 0, 0, 0);
        acc11 = __builtin_amdgcn_mfma_f32_16x16x32_bf16(ca1, cb1, acc11, 0, 0, 0);
        __syncthreads();
    }

    float* cls = cls_all + wv * (32 * 36);
#pragma unroll
    for (int osub = 0; osub < 2; ++osub) {
#pragma unroll
        for (int psub = 0; psub < 2; ++psub) {
            floatx4 d = osub ? (psub ? acc11 : acc10) : (psub ? acc01 : acc00);
#pragma unroll
            for (int r = 0; r < 4; ++r)
                cls[(osub * 16 + lhi * 4 + r) * 36 + psub * 16 + l15] = d[r];
        }
    }
#pragma unroll
    for (int i = 0; i < 4; ++i) {
        int o_loc = (lane >> 3) + i * 8;
        int pq = (lane & 7) * 4;
        int p = p0 + pw_loc + pq;
        if (p < HW) {
            float4 vv = *(float4*)&cls[o_loc * 36 + pq];
            int o = o_w + o_loc;
            float sh = shift[o];
            float4 so;
            float y;
            y = vv.x + sh; so.x = y / (1.f + __expf(-y));
            y = vv.y + sh; so.y = y / (1.f + __expf(-y));
            y = vv.z + sh; so.z = y / (1.f + __expf(-y));
            y = vv.w + sh; so.w = y / (1.f + __expf(-y));
            *(float4*)&out[((size_t)b * O + o) * HW + p] = so;
        }
    }
}

// merged gemm: L0 [0,800), L1 [800,1200), L2 [1200,1424)
__global__ __launch_bounds__(256) void k_gemmP_all(
    const unsigned short* __restrict__ xp0, const unsigned short* __restrict__ xp1,
    const unsigned short* __restrict__ xp2,
    const unsigned short* __restrict__ wb0, const unsigned short* __restrict__ wb1,
    const unsigned short* __restrict__ wb2,
    const float* __restrict__ shift, float* __restrict__ out) {
    __shared__ unsigned short xls[4096];
    __shared__ float cls[4 * 32 * 36];
    int bid = blockIdx.x;
    if (bid < 800) {
        gemmP_body<128, 160, 6400, 100>(bid, xp0, wb0, shift, out, xls, cls);
    } else if (bid < 1200) {
        gemmP_body<256, 288, 1600, 25>(bid - 800, xp1, wb1, shift + 128,
                                       out + 3276800, xls, cls);
    } else {
        gemmP_body<512, 544, 400, 7>(bid - 1200, xp2, wb2, shift + 384,
                                     out + 3276800 + 1638400, xls, cls);
    }
}

// ---------------------------------------------------------------------------
// K_gemm fused fallback (R3-validated, mode0 only; linear wb layout)
// ---------------------------------------------------------------------------
#define XLS_STRIDE 40
template <int O, int KP, int K, int HW, int TILES>
__global__ __launch_bounds__(256) void k_gemm(
    const float* __restrict__ f, const float* __restrict__ pre,
    const unsigned short* __restrict__ wb, const float* __restrict__ shift,
    float* __restrict__ out) {
    constexpr int CI = O;
    constexpr int OB = O / 64;
    __shared__ unsigned short xlsf[64 * XLS_STRIDE];

    int tid = threadIdx.x;
    int lane = tid & 63, wv = tid >> 6;
    int ob = blockIdx.x % OB;
    int rest = blockIdx.x / OB;
    int b = rest / TILES;
    int p0 = (rest % TILES) * 64;

    int l15 = lane & 15, lhi = lane >> 4;
    int o_w = ob * 64 + (wv & 1) * 32;
    int pw_loc = (wv >> 1) * 32;

    int c_l = tid >> 3;
    int pq = (tid & 7) * 8;
    const float* fbase = f + ((size_t)(b * TT + (TT - 1)) * CI) * HW;
    const float* pbase = pre + (size_t)b * HW * 4;

    const short8* aptr0 = (const short8*)(wb + (size_t)(o_w + l15) * KP + lhi * 8);
    const short8* aptr1 = (const short8*)(wb + (size_t)(o_w + 16 + l15) * KP + lhi * 8);

    floatx4 acc00 = {0.f, 0.f, 0.f, 0.f}, acc01 = acc00, acc10 = acc00, acc11 = acc00;

    for (int c0 = 0; c0 < KP; c0 += 32) {
        __syncthreads();
        {
            int c = c0 + c_l;
            float vals[8];
            if (c < CI) {
                const float* src = fbase + (size_t)c * HW + p0 + pq;
                if (p0 + pq + 7 < HW) {
                    float4 a = ((const float4*)src)[0];
                    float4 bq = ((const float4*)src)[1];
                    vals[0] = a.x; vals[1] = a.y; vals[2] = a.z; vals[3] = a.w;
                    vals[4] = bq.x; vals[5] = bq.y; vals[6] = bq.z; vals[7] = bq.w;
                } else {
#pragma unroll
                    for (int i = 0; i < 8; ++i) {
                        int p = p0 + pq + i;
                        vals[i] = (p < HW) ? src[i] : 0.f;
                    }
                }
            } else if (c < K) {
#pragma unroll
                for (int i = 0; i < 8; ++i) {
                    int p = p0 + pq + i;
                    vals[i] = (p < HW) ? pbase[(size_t)p * 4 + (c - CI)] : 0.f;
                }
            } else {
#pragma unroll
                for (int i = 0; i < 8; ++i) vals[i] = 0.f;
            }
#pragma unroll
            for (int i = 0; i < 8; ++i)
                xlsf[(pq + i) * XLS_STRIDE + c_l] = f2bf(vals[i]);
        }
        __syncthreads();

        short8 ca0 = aptr0[c0 >> 3];
        short8 ca1 = aptr1[c0 >> 3];
        short8 cb0 = *(const short8*)&xlsf[(pw_loc + l15) * XLS_STRIDE + lhi * 8];
        short8 cb1 = *(const short8*)&xlsf[(pw_loc + 16 + l15) * XLS_STRIDE + lhi * 8];
        acc00 = __builtin_amdgcn_mfma_f32_16x16x32_bf16(ca0, cb0, acc00, 0, 0, 0);
        acc01 = __builtin_amdgcn_mfma_f32_16x16x32_bf16(ca0, cb1, acc01, 0, 0, 0);
        acc10 = __builtin_amdgcn_mfma_f32_16x16x32_bf16(ca1, cb0, acc10, 0, 0, 0);
        acc11 = __builtin_amdgcn_mfma_f32_16x16x32_bf16(ca1, cb1, acc11, 0, 0, 0);
    }

#pragma unroll
    for (int osub = 0; osub < 2; ++osub) {
#pragma unroll
        for (int psub = 0; psub < 2; ++psub) {
            floatx4 d = osub ? (psub ? acc11 : acc10) : (psub ? acc01 : acc00);
            int p = p0 + pw_loc + psub * 16 + l15;
            int obase = o_w + osub * 16 + lhi * 4;
            if (p < HW) {
#pragma unroll
                for (int r = 0; r < 4; ++r) {
                    int o = obase + r;
                    float y = d[r] + shift[o];
                    float sig = 1.f / (1.f + __expf(-y));
                    out[((size_t)b * O + o) * HW + p] = y * sig;
                }
            }
        }
    }
}

// ---------------------------------------------------------------------------
extern "C" void kernel_launch(void* const* d_in, const int* in_sizes, int n_in,
                              void* d_out, int out_size, void* d_ws, size_t ws_size,
                              hipStream_t stream) {
    const float* f0 = (const float*)d_in[0];
    const float* f1 = (const float*)d_in[1];
    const float* f2 = (const float*)d_in[2];
    const float* w1 = (const float*)d_in[5];
    const float* g1 = (const float*)d_in[6];
    const float* b1 = (const float*)d_in[7];
    const float* m1 = (const float*)d_in[8];
    const float* v1 = (const float*)d_in[9];
    const float* w2_0 = (const float*)d_in[10];
    const float* g2_0 = (const float*)d_in[11];
    const float* b2_0 = (const float*)d_in[12];
    const float* m2_0 = (const float*)d_in[13];
    const float* v2_0 = (const float*)d_in[14];
    const float* w2_1 = (const float*)d_in[15];
    const float* g2_1 = (const float*)d_in[16];
    const float* b2_1 = (const float*)d_in[17];
    const float* m2_1 = (const float*)d_in[18];
    const float* v2_1 = (const float*)d_in[19];
    const float* w2_2 = (const float*)d_in[20];
    const float* g2_2 = (const float*)d_in[21];
    const float* b2_2 = (const float*)d_in[22];
    const float* m2_2 = (const float*)d_in[23];
    const float* v2_2 = (const float*)d_in[24];

    float* ws = (float*)d_ws;
    const size_t PADSZ = (size_t)BB * C2 * 28 * 32;          // 1,835,008 fl
    const size_t SP336_8 = (size_t)8 * BB * HW2 * 336;       // 4,300,800 fl
    const size_t SP8 = (size_t)8 * BB * HW2 * 256;           // 3,276,800 fl
    const size_t XP0 = 2048000, XP1 = 921600, XP2 = 487424;  // floats
    const size_t need2 =
        (SP336_8 + PADSZ + 6400 + 10240 + 36864 + 139264 + 896 + XP0 + XP1 + XP2) * 4;
    int mode = (ws_size >= need2) ? 2 : 0;

    float* out = (float*)d_out;

    if (mode == 2) {
        float* Spart = ws;
        float* pad = ws + SP336_8;
        float* psim = pad + PADSZ;
        unsigned short* wb0 = (unsigned short*)(psim + 6400);
        unsigned short* wb1 = wb0 + 20480;
        unsigned short* wb2 = wb1 + 73728;
        float* shift = (float*)(wb2 + 278528);
        float* xb = shift + 896;
        unsigned short* xp0 = (unsigned short*)xb;
        unsigned short* xp1 = (unsigned short*)(xb + XP0);
        unsigned short* xp2 = (unsigned short*)(xb + XP0 + XP1);

        k_prep_pad<<<dim3(3252), dim3(256), 0, stream>>>(
            f2, pad,
            w2_0, w2_1, w2_2,
            g2_0, b2_0, m2_0, v2_0,
            g2_1, b2_1, m2_1, v2_1,
            g2_2, b2_2, m2_2, v2_2,
            wb0, wb1, wb2, shift);
        k_cost_packf<<<dim3(4240), dim3(256), 0, stream>>>(
            f2, pad, Spart, f0, f1, xp0, xp1, xp2);
        k_smax_conv1<8, 336, true><<<dim3(1600), dim3(256), 0, stream>>>(
            Spart, w1, g1, b1, m1, v1, psim);
        k_pack_sim<<<dim3(132), dim3(256), 0, stream>>>(psim, xp0, xp1, xp2);
        k_gemmP_all<<<dim3(1424), dim3(256), 0, stream>>>(
            xp0, xp1, xp2, wb0, wb1, wb2, shift, out);
    } else {
        float* Spart = ws;
        float* psim = ws + SP8;
        float* pre0 = psim + 6400;
        float* pre1 = pre0 + 102400;
        unsigned short* wb0 = (unsigned short*)(pre1 + 25600);
        unsigned short* wb1 = wb0 + 20480;
        unsigned short* wb2 = wb1 + 73728;
        float* shift = (float*)(wb2 + 278528);

        k_prep<<<dim3(1460), dim3(256), 0, stream>>>(
            w2_0, w2_1, w2_2,
            g2_0, b2_0, m2_0, v2_0,
            g2_1, b2_1, m2_1, v2_1,
            g2_2, b2_2, m2_2, v2_2,
            wb0, wb1, wb2, shift);
        k_cost<8, 256><<<dim3(8 * 108), dim3(128), 0, stream>>>(f2, Spart);
        k_smax_conv1<8, 256, false><<<dim3(1600), dim3(256), 0, stream>>>(
            Spart, w1, g1, b1, m1, v1, psim);
        k_resize<<<dim3(125), dim3(256), 0, stream>>>(psim, pre0, pre1);
        k_gemm<128, 160, 132, 6400, 100><<<dim3(800), dim3(256), 0, stream>>>(
            f0, pre0, wb0, shift, out);
        k_gemm<256, 288, 260, 1600, 25><<<dim3(400), dim3(256), 0, stream>>>(
            f1, pre1, wb1, shift + 128, out + 3276800);
        k_gemm<512, 544, 516, 400, 7><<<dim3(224), dim3(256), 0, stream>>>(
            f2, psim, wb2, shift + 384, out + 3276800 + 1638400);
    }
}